// Round 10
// baseline (37632.547 us; speedup 1.0000x reference)
//
#include <hip/hip_runtime.h>
#include <hip/hip_bf16.h>

// LSTM classifier: emb gather -> input GEMM (fp16 MFMA) -> persistent
// recurrence with DATA-CARRIED sync (poison-tagged h words; no flags/fences/
// cross-WG barriers) + dual-XOR conflict-free LDS staging -> logits.
//
// Workspace layout (bytes):
//   emb16   @ 0          : 50257*1024*2 = 102,926,336
//   wih16   @ 102926336  : 4096*1024*2  =   8,388,608
//   wr16    @ 111314944  : 4096*1024*2  =   8,388,608   (W_hh reordered, fp16)
//   bias    @ 119703552  : 4096*4       =      16,384   (b_ih + b_hh, f32)
//   xg      @ 119719936  : 65536*4096*2 = 536,870,912   (x_gates fp16, [t][b][R'])
//   h_all   @ 656590848  : 2049*32*1024*2 = 134,283,264 (h; t>=1 poisoned 0xFFFF per launch)
//   total: 790,874,112

typedef _Float16 f16;
typedef _Float16 f16x8 __attribute__((ext_vector_type(8)));
typedef _Float16 f16x4 __attribute__((ext_vector_type(4)));
typedef float    f32x4 __attribute__((ext_vector_type(4)));
typedef unsigned long long u64;

#define B_    32
#define T_    2048
#define H_    1024
#define G4_   4096

__device__ __forceinline__ void gl_lds16(const void* g, void* l) {
  __builtin_amdgcn_global_load_lds(
      (const __attribute__((address_space(1))) void*)g,
      (__attribute__((address_space(3))) void*)l, 16, 0, 0);
}

// agent-scope (LLC) 8B store — write-through past the non-coherent XCD L2s
__device__ __forceinline__ void llc_st64(void* p, u64 v) {
  __hip_atomic_store((u64*)p, v, __ATOMIC_RELAXED, __HIP_MEMORY_SCOPE_AGENT);
}

// fast activations: v_exp_f32 + v_rcp_f32 (no libm branches on critical path)
__device__ __forceinline__ float fast_sigmoid(float v) {
  return __builtin_amdgcn_rcpf(1.f + __expf(-v));
}
__device__ __forceinline__ float fast_tanh(float v) {
  return 1.f - 2.f * __builtin_amdgcn_rcpf(1.f + __expf(2.f * v));
}

// ---------------- conversions ----------------

__global__ void k_cvt_f16(const float* __restrict__ in, f16* __restrict__ out, long n4) {
  long i = (long)blockIdx.x * blockDim.x + threadIdx.x;
  if (i >= n4) return;
  float4 v = ((const float4*)in)[i];
  f16x4 o; o[0] = (f16)v.x; o[1] = (f16)v.y; o[2] = (f16)v.z; o[3] = (f16)v.w;
  *(f16x4*)(out + i * 4) = o;
}

// W_hh row (q*1024 + j) -> wr16 row R' = (j>>4)*64 + (j&15)*4 + q; fp16.
// => WG wid owns contiguous rows [wid*64, wid*64+64) = h-dims [wid*16, +16).
__global__ void k_whh_reorder(const float* __restrict__ whh, f16* __restrict__ wr) {
  unsigned i = blockIdx.x * blockDim.x + threadIdx.x;   // one thread per 8 elems
  unsigned e0 = i * 8;
  unsigned R = e0 >> 10, k = e0 & 1023;
  unsigned q = R >> 10, j = R & 1023;
  unsigned outR = ((j >> 4) << 6) + ((j & 15) << 2) + q;
  float4 v0 = ((const float4*)whh)[e0 / 4];
  float4 v1 = ((const float4*)whh)[e0 / 4 + 1];
  f16x8 o;
  o[0] = (f16)v0.x; o[1] = (f16)v0.y; o[2] = (f16)v0.z; o[3] = (f16)v0.w;
  o[4] = (f16)v1.x; o[5] = (f16)v1.y; o[6] = (f16)v1.z; o[7] = (f16)v1.w;
  *(f16x8*)&wr[((size_t)outR << 10) + k] = o;
}

__global__ void k_bias(const float* __restrict__ bi, const float* __restrict__ bh,
                       float* __restrict__ bo) {
  unsigned i = blockIdx.x * blockDim.x + threadIdx.x;
  if (i < G4_) bo[i] = bi[i] + bh[i];
}

// ---------------- input GEMM: xg[m][R'(n)] = emb[seq] @ W_ih^T + bias ----------------
// m = t*32 + b (so xg layout is [t][b][R']); 128x128 tile, BK=64, 4 waves.

__global__ __launch_bounds__(256) void k_gemm_xg(
    const int* __restrict__ seq, const f16* __restrict__ emb16,
    const f16* __restrict__ wih16, const float* __restrict__ bias,
    f16* __restrict__ xg) {
  __shared__ f16 As[128 * 64];
  __shared__ f16 Bs[128 * 64];
  const unsigned tid = threadIdx.x;
  const unsigned w = tid >> 6, lane = tid & 63;
  const unsigned bid = blockIdx.x;
  const unsigned tn = bid & 31, tm = bid >> 5;
  const unsigned wm = (w >> 1) * 64, wn = (w & 1) * 64;

  f32x4 zero = {0.f, 0.f, 0.f, 0.f};
  f32x4 acc[4][4];
#pragma unroll
  for (int i = 0; i < 4; ++i)
#pragma unroll
    for (int j = 0; j < 4; ++j) acc[i][j] = zero;

  for (unsigned kk = 0; kk < 16; ++kk) {
    const unsigned k0 = kk * 64;
#pragma unroll
    for (unsigned c = 0; c < 4; ++c) {
      unsigned idx = c * 256 + tid;
      unsigned row = idx >> 3, ch = idx & 7;
      unsigned chs = ch ^ (row & 7);
      unsigned m = tm * 128 + row;
      unsigned t = m >> 5, b = m & 31;
      int e = seq[b * 2048 + t];
      const f16* src = emb16 + ((size_t)e << 10) + k0 + chs * 8;
      gl_lds16(src, (char*)As + c * 4096 + w * 1024);
    }
#pragma unroll
    for (unsigned c = 0; c < 4; ++c) {
      unsigned idx = c * 256 + tid;
      unsigned row = idx >> 3, ch = idx & 7;
      unsigned chs = ch ^ (row & 7);
      unsigned n = tn * 128 + row;
      const f16* src = wih16 + ((size_t)n << 10) + k0 + chs * 8;
      gl_lds16(src, (char*)Bs + c * 4096 + w * 1024);
    }
    __syncthreads();
#pragma unroll
    for (unsigned ks = 0; ks < 2; ++ks) {
      f16x8 af[4], bf[4];
      unsigned kc = ks * 4 + (lane >> 4);
#pragma unroll
      for (unsigned fm = 0; fm < 4; ++fm) {
        unsigned r = wm + fm * 16 + (lane & 15);
        af[fm] = *(const f16x8*)&As[r * 64 + ((kc ^ (r & 7)) << 3)];
      }
#pragma unroll
      for (unsigned fn = 0; fn < 4; ++fn) {
        unsigned r = wn + fn * 16 + (lane & 15);
        bf[fn] = *(const f16x8*)&Bs[r * 64 + ((kc ^ (r & 7)) << 3)];
      }
#pragma unroll
      for (unsigned fm = 0; fm < 4; ++fm)
#pragma unroll
        for (unsigned fn = 0; fn < 4; ++fn)
          acc[fm][fn] = __builtin_amdgcn_mfma_f32_16x16x32_f16(af[fm], bf[fn], acc[fm][fn], 0, 0, 0);
    }
    __syncthreads();
  }
  // epilogue: + bias, fp16 store into gate-interleaved layout R'
#pragma unroll
  for (unsigned fn = 0; fn < 4; ++fn) {
    unsigned n = tn * 128 + wn + fn * 16 + (lane & 15);
    unsigned q = n >> 10, j = n & 1023;
    unsigned Rp = ((j >> 4) << 6) + ((j & 15) << 2) + q;
    float bv = bias[n];
#pragma unroll
    for (unsigned fm = 0; fm < 4; ++fm) {
#pragma unroll
      for (unsigned rg = 0; rg < 4; ++rg) {
        unsigned m = tm * 128 + wm + fm * 16 + (lane >> 4) * 4 + rg;
        xg[(size_t)m * G4_ + Rp] = (f16)(acc[fm][fn][rg] + bv);
      }
    }
  }
}

// ---------------- persistent LSTM recurrence, data-carried sync ----------------
// 64 WGs x 512 threads (8 waves = 2 M-tiles x 4 N-tiles). WG wid owns h-dims
// [wid*16,+16). W_hh slice: k<512 in 64KB LDS, k>=512 in 64 asm-pinned VGPRs.
// h_all[t>=1] poisoned 0xFFFF per launch (h in (-1,1) -> 0xFFFF impossible).
// Per step: thread owns a 128B slice of h_{t-1}: issue 8x16B sc0 sc1 loads;
// granules that clear the poison check are ds_written to Hl IMMEDIATELY
// (overlaps LDS writes with the LLC wait); only stragglers re-issue.
// Hl swizzle is DUAL-XOR: pos = cc ^ (row&7) ^ ((cc>>3)&7) on BOTH the write
// and the read side -> staging writes drop from 16-way conflict to ~none
// (the R8 6.7e8-cycle SQ_LDS_BANK_CONFLICT), reads stay at the b128 minimum.

__global__ __launch_bounds__(512) void k_lstm(
    const f16* __restrict__ xg, const f16* __restrict__ wr16,
    f16* __restrict__ h_all) {
  __shared__ f16 Wl[64 * 512];    // 64 KB: W_hh slice, k < 512
  __shared__ f16 Hl[32 * 1024];   // 64 KB: h_{t-1} staging tile
  const unsigned tid = threadIdx.x;
  const unsigned w = tid >> 6, lane = tid & 63;
  const unsigned wid = blockIdx.x;          // 0..63
  const unsigned mt = w >> 2, nt = w & 3;

  // stage W k<512 (64 rows x 64 16B-chunks), source-swizzled, linear LDS dest
  for (unsigned c = 0; c < 8; ++c) {
    unsigned idx = c * 512 + tid;
    unsigned row = idx >> 6, ch = idx & 63;
    unsigned chs = ch ^ (row & 7);
    const f16* src = wr16 + (((size_t)wid * 64 + row) << 10) + chs * 8;
    gl_lds16(src, (char*)Wl + c * 8192 + w * 1024);
  }

  const unsigned rl = lane & 15, hi = lane >> 4;
  const unsigned q = rl & 3;                 // gate id within quad
  const unsigned rWl = nt * 16 + rl;         // local W row 0..63
  const unsigned bB = mt * 16 + hi * 4;      // batch base of this lane's 4 accs
  const unsigned d0 = wid * 16 + nt * 4;     // first h-dim of this wave's quad row
  const unsigned arow = mt * 16 + rl;        // A-tile row (batch) in Hl

  // B-frags k in [512,1024): pinned in VGPRs via asm (cannot sink - R3 lesson)
  f16x8 breg[16];
  {
    const f16* wp = wr16 + (((size_t)wid * 64 + rWl) << 10) + 512 + hi * 8;
#pragma unroll
    for (int j = 0; j < 16; ++j) {
      asm volatile("global_load_dwordx4 %0, %1, off\n\ts_waitcnt vmcnt(0)"
                   : "=v"(breg[j]) : "v"(wp + j * 32) : "memory");
    }
  }
  __syncthreads();   // Wl staged + breg loaded

  // staging assignment: batch row = tid>>4, f16 col base = (tid&15)*64 (128B)
  const unsigned srow = tid >> 4;
  const unsigned scg = (tid & 15) * 8;       // first 16B-chunk index (cc = scg+j)
  float c_st[4] = {0.f, 0.f, 0.f, 0.f};

  for (unsigned t = 1; t <= (unsigned)T_; ++t) {
    // ---- issue the 8 A-slice loads first (critical path; sc0 sc1 -> LLC) ----
    const f16* gp = h_all + ((size_t)(t - 1) * B_ + srow) * H_ + scg * 8;
    f16x8 st[8];
#pragma unroll
    for (int j = 0; j < 8; ++j)
      asm volatile("global_load_dwordx4 %0, %1, off sc0 sc1"
                   : "=v"(st[j]) : "v"(gp + j * 8) : "memory");
    // x_gates for step t (plain loads, L2-cached; complete under the wait)
    float xv[4];
    {
      const f16* xp = xg + ((size_t)(t - 1) * B_ + bB) * G4_ + wid * 64 + rWl;
#pragma unroll
      for (int z = 0; z < 4; ++z) xv[z] = (float)xp[(size_t)z * G4_];
    }
    asm volatile("s_waitcnt vmcnt(0)" ::: "memory");
    __builtin_amdgcn_sched_barrier(0);   // rule #18: pin checks after the wait
    // ---- per-granule: ds_write ready granules now; re-issue only stragglers ----
    unsigned done = 0;
    while (true) {
#pragma unroll
      for (int j = 0; j < 8; ++j) {
        if (!(done & (1u << j))) {
          union { f16x8 v; u64 u[2]; } uu; uu.v = st[j];
          if ((uu.u[0] != ~0ull) && (uu.u[1] != ~0ull)) {
            unsigned cc = scg + j;
            unsigned pos = cc ^ (srow & 7) ^ ((cc >> 3) & 7);   // dual-XOR swizzle
            *(f16x8*)&Hl[srow * 1024 + (pos << 3)] = st[j];
            done |= (1u << j);
          }
        }
      }
      if (done == 0xFFu) break;
      __builtin_amdgcn_s_sleep(1);
#pragma unroll
      for (int j = 0; j < 8; ++j) {
        if (!(done & (1u << j)))
          asm volatile("global_load_dwordx4 %0, %1, off sc0 sc1"
                       : "+v"(st[j]) : "v"(gp + j * 8) : "memory");
      }
      asm volatile("s_waitcnt vmcnt(0)" ::: "memory");
      __builtin_amdgcn_sched_barrier(0);
    }
    __syncthreads();   // h-tile ready for all waves

    // ---- gates = h_{t-1}[m-tile] @ Whh_slice[n-tile]^T (A from Hl) ----
    f32x4 acc0 = {0.f, 0.f, 0.f, 0.f};
    f32x4 acc1 = {0.f, 0.f, 0.f, 0.f};
#pragma unroll
    for (unsigned ks = 0; ks < 16; ks += 2) {
      unsigned c0 = ks * 4 + hi, c1 = c0 + 4;
      unsigned p0 = c0 ^ (arow & 7) ^ ((c0 >> 3) & 7);
      unsigned p1 = c1 ^ (arow & 7) ^ ((c1 >> 3) & 7);
      f16x8 a0 = *(const f16x8*)&Hl[arow * 1024 + (p0 << 3)];
      f16x8 a1 = *(const f16x8*)&Hl[arow * 1024 + (p1 << 3)];
      f16x8 b0 = *(const f16x8*)&Wl[rWl * 512 + ((c0 ^ (rWl & 7)) << 3)];
      f16x8 b1 = *(const f16x8*)&Wl[rWl * 512 + ((c1 ^ (rWl & 7)) << 3)];
      acc0 = __builtin_amdgcn_mfma_f32_16x16x32_f16(a0, b0, acc0, 0, 0, 0);
      acc1 = __builtin_amdgcn_mfma_f32_16x16x32_f16(a1, b1, acc1, 0, 0, 0);
    }
#pragma unroll
    for (unsigned ks = 16; ks < 32; ks += 2) {
      unsigned c0 = ks * 4 + hi, c1 = c0 + 4;
      unsigned p0 = c0 ^ (arow & 7) ^ ((c0 >> 3) & 7);
      unsigned p1 = c1 ^ (arow & 7) ^ ((c1 >> 3) & 7);
      f16x8 a0 = *(const f16x8*)&Hl[arow * 1024 + (p0 << 3)];
      f16x8 a1 = *(const f16x8*)&Hl[arow * 1024 + (p1 << 3)];
      acc0 = __builtin_amdgcn_mfma_f32_16x16x32_f16(a0, breg[ks - 16], acc0, 0, 0, 0);
      acc1 = __builtin_amdgcn_mfma_f32_16x16x32_f16(a1, breg[ks - 15], acc1, 0, 0, 0);
    }
    __syncthreads();   // all Hl reads done -> next iteration may overwrite

    // ---- activations + state update (quad holds i,f,g,o of one (d, b-set)) ----
    float hv[4];
#pragma unroll
    for (int z = 0; z < 4; ++z) {
      float v = acc0[z] + acc1[z] + xv[z];
      float a = (q == 2) ? fast_tanh(v) : fast_sigmoid(v);
      float A1 = __shfl_xor(a, 1, 64);
      float A2 = __shfl_xor(a, 2, 64);
      float A3 = __shfl_xor(a, 3, 64);
      float iact = (q == 0) ? a  : (q == 1) ? A1 : (q == 2) ? A2 : A3;
      float fact = (q == 0) ? A1 : (q == 1) ? a  : (q == 2) ? A3 : A2;
      float gact = (q == 0) ? A2 : (q == 1) ? A3 : (q == 2) ? a  : A1;
      float oact = (q == 0) ? A3 : (q == 1) ? A2 : (q == 2) ? A1 : a;
      float cn = fact * c_st[z] + iact * gact;
      c_st[z] = cn;
      hv[z] = oact * fast_tanh(cn);
    }
    // ---- pack h(d0..d0+3) per batch into 8B, store via sc1 (16/wave) ----
    unsigned sb = lane & 48;   // hi*16
    float g[4][4];
#pragma unroll
    for (int j = 0; j < 4; ++j) {
      g[j][0] = __shfl(hv[0], (int)(sb | (j << 2)), 64);
      g[j][1] = __shfl(hv[1], (int)(sb | (j << 2)), 64);
      g[j][2] = __shfl(hv[2], (int)(sb | (j << 2)), 64);
      g[j][3] = __shfl(hv[3], (int)(sb | (j << 2)), 64);
    }
    if ((rl & 3) == 0) {
      unsigned zb = rl >> 2;   // this lane stores batch bB+zb
      union { f16 h4[4]; u64 u; } pk;
#pragma unroll
      for (int j = 0; j < 4; ++j) {
        float tv = (zb == 0) ? g[j][0] : (zb == 1) ? g[j][1]
                 : (zb == 2) ? g[j][2] : g[j][3];
        pk.h4[j] = (f16)tv;
      }
      f16* hw = h_all + ((size_t)t * B_ + bB + zb) * H_ + d0;
      llc_st64(hw, pk.u);
    }
    // no release: stores drain under the next step's vmcnt(0)
  }
}

// ---------------- logits: out[b][t][c] = relu(h[t+1]) . W_score[c] ----------------

__global__ __launch_bounds__(256) void k_logits(
    const f16* __restrict__ h_all, const float* __restrict__ wsc,
    float* __restrict__ out) {
  __shared__ float Ws[2048];
  unsigned tid = threadIdx.x;
  for (unsigned i = tid; i < 512; i += 256) ((float4*)Ws)[i] = ((const float4*)wsc)[i];
  __syncthreads();
  unsigned w = tid >> 6, lane = tid & 63;
  unsigned base = blockIdx.x * 64 + w * 16;
  for (unsigned i = 0; i < 16; ++i) {
    unsigned idx = base + i;                // 0..65535
    unsigned tt = idx >> 5, b = idx & 31;
    const f16* hp = h_all + ((size_t)(idx + 32)) * H_ + lane * 16;
    f16x8 ha = *(const f16x8*)hp;
    f16x8 hb = *(const f16x8*)(hp + 8);
    float s0 = 0.f, s1 = 0.f;
#pragma unroll
    for (int z = 0; z < 8; ++z) {
      float hv = fmaxf((float)ha[z], 0.f);
      s0 += hv * Ws[lane * 16 + z];
      s1 += hv * Ws[1024 + lane * 16 + z];
    }
#pragma unroll
    for (int z = 0; z < 8; ++z) {
      float hv = fmaxf((float)hb[z], 0.f);
      s0 += hv * Ws[lane * 16 + 8 + z];
      s1 += hv * Ws[1024 + lane * 16 + 8 + z];
    }
#pragma unroll
    for (int off = 32; off; off >>= 1) {
      s0 += __shfl_xor(s0, off, 64);
      s1 += __shfl_xor(s1, off, 64);
    }
    if (lane == 0) {
      out[((size_t)b * T_ + tt) * 2 + 0] = s0;
      out[((size_t)b * T_ + tt) * 2 + 1] = s1;
    }
  }
}

// ---------------- launch ----------------

extern "C" void kernel_launch(void* const* d_in, const int* in_sizes, int n_in,
                              void* d_out, int out_size, void* d_ws, size_t ws_size,
                              hipStream_t stream) {
  const int*   seq = (const int*)d_in[0];
  const float* emb = (const float*)d_in[1];
  const float* wih = (const float*)d_in[2];
  const float* whh = (const float*)d_in[3];
  const float* bih = (const float*)d_in[4];
  const float* bhh = (const float*)d_in[5];
  const float* wsc = (const float*)d_in[6];
  float* out = (float*)d_out;
  char* ws = (char*)d_ws;

  const size_t NEED = 790874112ull;
  if (ws_size < NEED) return;  // workspace too small: output stays zero (detectable)

  f16*   emb16 = (f16*)(ws);
  f16*   wih16 = (f16*)(ws + 102926336ull);
  f16*   wr16  = (f16*)(ws + 111314944ull);
  float* bias  = (float*)(ws + 119703552ull);
  f16*   xg    = (f16*)(ws + 119719936ull);
  f16*   h_all = (f16*)(ws + 656590848ull);

  hipMemsetAsync(h_all, 0, (size_t)B_ * H_ * 2, stream);                // h_0 = 0
  hipMemsetAsync((char*)h_all + (size_t)B_ * H_ * 2, 0xFF,
                 (size_t)T_ * B_ * H_ * 2, stream);                     // poison h_1..h_T

  k_cvt_f16<<<50257, 256, 0, stream>>>(emb, emb16, 12865792L);
  k_cvt_f16<<<4096, 256, 0, stream>>>(wih, wih16, 1048576L);
  k_whh_reorder<<<2048, 256, 0, stream>>>(whh, wr16);
  k_bias<<<16, 256, 0, stream>>>(bih, bhh, bias);

  k_gemm_xg<<<16384, 256, 0, stream>>>(seq, emb16, wih16, bias, xg);
  k_lstm<<<64, 512, 0, stream>>>(xg, wr16, h_all);
  k_logits<<<1024, 256, 0, stream>>>(h_all, wsc, out);
}

// Round 11
// 20084.096 us; speedup vs baseline: 1.8737x; 1.8737x over previous
//
#include <hip/hip_runtime.h>
#include <hip/hip_bf16.h>

// LSTM classifier: emb gather -> input GEMM (fp16 MFMA) -> persistent
// recurrence with DATA-CARRIED sync (poison-tagged h words; no flags, no
// fences, no cross-WG barriers) -> logits.
// R11 = R8 byte-identical structure + dual-XOR LDS swizzle (the single
// lever R10 validated at counter level).
//
// Workspace layout (bytes):
//   emb16   @ 0          : 50257*1024*2 = 102,926,336
//   wih16   @ 102926336  : 4096*1024*2  =   8,388,608
//   wr16    @ 111314944  : 4096*1024*2  =   8,388,608   (W_hh reordered, fp16)
//   bias    @ 119703552  : 4096*4       =      16,384   (b_ih + b_hh, f32)
//   xg      @ 119719936  : 65536*4096*2 = 536,870,912   (x_gates fp16, [t][b][R'])
//   h_all   @ 656590848  : 2049*32*1024*2 = 134,283,264 (h; t>=1 poisoned 0xFFFF per launch)
//   total: 790,874,112

typedef _Float16 f16;
typedef _Float16 f16x8 __attribute__((ext_vector_type(8)));
typedef _Float16 f16x4 __attribute__((ext_vector_type(4)));
typedef float    f32x4 __attribute__((ext_vector_type(4)));
typedef unsigned long long u64;

#define B_    32
#define T_    2048
#define H_    1024
#define G4_   4096

__device__ __forceinline__ void gl_lds16(const void* g, void* l) {
  __builtin_amdgcn_global_load_lds(
      (const __attribute__((address_space(1))) void*)g,
      (__attribute__((address_space(3))) void*)l, 16, 0, 0);
}

// agent-scope (LLC) 8B store — write-through past the non-coherent XCD L2s
__device__ __forceinline__ void llc_st64(void* p, u64 v) {
  __hip_atomic_store((u64*)p, v, __ATOMIC_RELAXED, __HIP_MEMORY_SCOPE_AGENT);
}

// fast activations: v_exp_f32 + v_rcp_f32 (no libm branches on critical path)
__device__ __forceinline__ float fast_sigmoid(float v) {
  return __builtin_amdgcn_rcpf(1.f + __expf(-v));
}
__device__ __forceinline__ float fast_tanh(float v) {
  return 1.f - 2.f * __builtin_amdgcn_rcpf(1.f + __expf(2.f * v));
}

// ---------------- conversions ----------------

__global__ void k_cvt_f16(const float* __restrict__ in, f16* __restrict__ out, long n4) {
  long i = (long)blockIdx.x * blockDim.x + threadIdx.x;
  if (i >= n4) return;
  float4 v = ((const float4*)in)[i];
  f16x4 o; o[0] = (f16)v.x; o[1] = (f16)v.y; o[2] = (f16)v.z; o[3] = (f16)v.w;
  *(f16x4*)(out + i * 4) = o;
}

// W_hh row (q*1024 + j) -> wr16 row R' = (j>>4)*64 + (j&15)*4 + q; fp16.
// => WG wid owns contiguous rows [wid*64, wid*64+64) = h-dims [wid*16, +16).
__global__ void k_whh_reorder(const float* __restrict__ whh, f16* __restrict__ wr) {
  unsigned i = blockIdx.x * blockDim.x + threadIdx.x;   // one thread per 8 elems
  unsigned e0 = i * 8;
  unsigned R = e0 >> 10, k = e0 & 1023;
  unsigned q = R >> 10, j = R & 1023;
  unsigned outR = ((j >> 4) << 6) + ((j & 15) << 2) + q;
  float4 v0 = ((const float4*)whh)[e0 / 4];
  float4 v1 = ((const float4*)whh)[e0 / 4 + 1];
  f16x8 o;
  o[0] = (f16)v0.x; o[1] = (f16)v0.y; o[2] = (f16)v0.z; o[3] = (f16)v0.w;
  o[4] = (f16)v1.x; o[5] = (f16)v1.y; o[6] = (f16)v1.z; o[7] = (f16)v1.w;
  *(f16x8*)&wr[((size_t)outR << 10) + k] = o;
}

__global__ void k_bias(const float* __restrict__ bi, const float* __restrict__ bh,
                       float* __restrict__ bo) {
  unsigned i = blockIdx.x * blockDim.x + threadIdx.x;
  if (i < G4_) bo[i] = bi[i] + bh[i];
}

// ---------------- input GEMM: xg[m][R'(n)] = emb[seq] @ W_ih^T + bias ----------------
// m = t*32 + b (so xg layout is [t][b][R']); 128x128 tile, BK=64, 4 waves.

__global__ __launch_bounds__(256) void k_gemm_xg(
    const int* __restrict__ seq, const f16* __restrict__ emb16,
    const f16* __restrict__ wih16, const float* __restrict__ bias,
    f16* __restrict__ xg) {
  __shared__ f16 As[128 * 64];
  __shared__ f16 Bs[128 * 64];
  const unsigned tid = threadIdx.x;
  const unsigned w = tid >> 6, lane = tid & 63;
  const unsigned bid = blockIdx.x;
  const unsigned tn = bid & 31, tm = bid >> 5;
  const unsigned wm = (w >> 1) * 64, wn = (w & 1) * 64;

  f32x4 zero = {0.f, 0.f, 0.f, 0.f};
  f32x4 acc[4][4];
#pragma unroll
  for (int i = 0; i < 4; ++i)
#pragma unroll
    for (int j = 0; j < 4; ++j) acc[i][j] = zero;

  for (unsigned kk = 0; kk < 16; ++kk) {
    const unsigned k0 = kk * 64;
#pragma unroll
    for (unsigned c = 0; c < 4; ++c) {
      unsigned idx = c * 256 + tid;
      unsigned row = idx >> 3, ch = idx & 7;
      unsigned chs = ch ^ (row & 7);
      unsigned m = tm * 128 + row;
      unsigned t = m >> 5, b = m & 31;
      int e = seq[b * 2048 + t];
      const f16* src = emb16 + ((size_t)e << 10) + k0 + chs * 8;
      gl_lds16(src, (char*)As + c * 4096 + w * 1024);
    }
#pragma unroll
    for (unsigned c = 0; c < 4; ++c) {
      unsigned idx = c * 256 + tid;
      unsigned row = idx >> 3, ch = idx & 7;
      unsigned chs = ch ^ (row & 7);
      unsigned n = tn * 128 + row;
      const f16* src = wih16 + ((size_t)n << 10) + k0 + chs * 8;
      gl_lds16(src, (char*)Bs + c * 4096 + w * 1024);
    }
    __syncthreads();
#pragma unroll
    for (unsigned ks = 0; ks < 2; ++ks) {
      f16x8 af[4], bf[4];
      unsigned kc = ks * 4 + (lane >> 4);
#pragma unroll
      for (unsigned fm = 0; fm < 4; ++fm) {
        unsigned r = wm + fm * 16 + (lane & 15);
        af[fm] = *(const f16x8*)&As[r * 64 + ((kc ^ (r & 7)) << 3)];
      }
#pragma unroll
      for (unsigned fn = 0; fn < 4; ++fn) {
        unsigned r = wn + fn * 16 + (lane & 15);
        bf[fn] = *(const f16x8*)&Bs[r * 64 + ((kc ^ (r & 7)) << 3)];
      }
#pragma unroll
      for (unsigned fm = 0; fm < 4; ++fm)
#pragma unroll
        for (unsigned fn = 0; fn < 4; ++fn)
          acc[fm][fn] = __builtin_amdgcn_mfma_f32_16x16x32_f16(af[fm], bf[fn], acc[fm][fn], 0, 0, 0);
    }
    __syncthreads();
  }
  // epilogue: + bias, fp16 store into gate-interleaved layout R'
#pragma unroll
  for (unsigned fn = 0; fn < 4; ++fn) {
    unsigned n = tn * 128 + wn + fn * 16 + (lane & 15);
    unsigned q = n >> 10, j = n & 1023;
    unsigned Rp = ((j >> 4) << 6) + ((j & 15) << 2) + q;
    float bv = bias[n];
#pragma unroll
    for (unsigned fm = 0; fm < 4; ++fm) {
#pragma unroll
      for (unsigned rg = 0; rg < 4; ++rg) {
        unsigned m = tm * 128 + wm + fm * 16 + (lane >> 4) * 4 + rg;
        xg[(size_t)m * G4_ + Rp] = (f16)(acc[fm][fn][rg] + bv);
      }
    }
  }
}

// ---------------- persistent LSTM recurrence, data-carried sync ----------------
// 64 WGs x 512 threads (8 waves = 2 M-tiles x 4 N-tiles). WG wid owns h-dims
// [wid*16, wid*16+16). W_hh slice: k<512 in 64KB LDS, k>=512 in 64 VGPRs/lane
// (asm-pinned). h_all[t>=1] poisoned 0xFFFF per launch; h in (-1,1) so 0xFFFF
// (f16 -NaN) never occurs naturally.
// Per step (R8 structure, unchanged): each thread spin-loads its own 128B
// slice of h_{t-1} (8x16B sc0 sc1 loads, whole-slice retry) until no 8B
// granule is all-poison -> ds_write into 64KB DUAL-XOR-swizzled LDS h-tile
// (pos = cc ^ (row&7) ^ ((cc>>3)&7); spreads each write instr across 8
// bank-quads instead of 4 -> kills the 6.7e8-cy staging conflict) -> barrier
// -> MFMA -> barrier -> activations -> pack 4 dims/8B -> 16 sc1 stores/wave.
// The spin IS the sync: no flags, no fences, no release waits.

__global__ __launch_bounds__(512) void k_lstm(
    const f16* __restrict__ xg, const f16* __restrict__ wr16,
    f16* __restrict__ h_all) {
  __shared__ f16 Wl[64 * 512];    // 64 KB: W_hh slice, k < 512
  __shared__ f16 Hl[32 * 1024];   // 64 KB: h_{t-1} staging tile
  const unsigned tid = threadIdx.x;
  const unsigned w = tid >> 6, lane = tid & 63;
  const unsigned wid = blockIdx.x;          // 0..63
  const unsigned mt = w >> 2, nt = w & 3;

  // stage W k<512 (64 rows x 64 16B-chunks), source-swizzled, linear LDS dest
  for (unsigned c = 0; c < 8; ++c) {
    unsigned idx = c * 512 + tid;
    unsigned row = idx >> 6, ch = idx & 63;
    unsigned chs = ch ^ (row & 7);
    const f16* src = wr16 + (((size_t)wid * 64 + row) << 10) + chs * 8;
    gl_lds16(src, (char*)Wl + c * 8192 + w * 1024);
  }

  const unsigned rl = lane & 15, hi = lane >> 4;
  const unsigned q = rl & 3;                 // gate id within quad
  const unsigned rWl = nt * 16 + rl;         // local W row 0..63
  const unsigned bB = mt * 16 + hi * 4;      // batch base of this lane's 4 accs
  const unsigned d0 = wid * 16 + nt * 4;     // first h-dim of this wave's quad row
  const unsigned arow = mt * 16 + rl;        // A-tile row (batch) in Hl

  // B-frags k in [512,1024): pinned in VGPRs via asm (cannot sink - R3 lesson)
  f16x8 breg[16];
  {
    const f16* wp = wr16 + (((size_t)wid * 64 + rWl) << 10) + 512 + hi * 8;
#pragma unroll
    for (int j = 0; j < 16; ++j) {
      asm volatile("global_load_dwordx4 %0, %1, off\n\ts_waitcnt vmcnt(0)"
                   : "=v"(breg[j]) : "v"(wp + j * 32) : "memory");
    }
  }
  __syncthreads();   // Wl staged + breg loaded

  // staging assignment: batch row = tid>>4, f16 col base = (tid&15)*64 (128B)
  const unsigned srow = tid >> 4;
  const unsigned scol = (tid & 15) << 6;
  float c_st[4] = {0.f, 0.f, 0.f, 0.f};

  for (unsigned t = 1; t <= (unsigned)T_; ++t) {
    // x_gates for step t (plain loads, L2-cached; complete under the spin)
    float xv[4];
    {
      const f16* xp = xg + ((size_t)(t - 1) * B_ + bB) * G4_ + wid * 64 + rWl;
#pragma unroll
      for (int z = 0; z < 4; ++z) xv[z] = (float)xp[(size_t)z * G4_];
    }
    // ---- data-driven staging: spin on own 128B slice of h_{t-1} ----
    const f16* gp = h_all + ((size_t)(t - 1) * B_ + srow) * H_ + scol;
    f16x8 st[8];
    while (true) {
#pragma unroll
      for (int j = 0; j < 8; ++j)
        asm volatile("global_load_dwordx4 %0, %1, off sc0 sc1"
                     : "=v"(st[j]) : "v"(gp + j * 8));
      asm volatile("s_waitcnt vmcnt(0)" ::: "memory");
      __builtin_amdgcn_sched_barrier(0);   // rule #18: pin the check after the wait
      bool ok = true;
#pragma unroll
      for (int j = 0; j < 8; ++j) {
        union { f16x8 v; u64 u[2]; } uu; uu.v = st[j];
        ok = ok && (uu.u[0] != ~0ull) && (uu.u[1] != ~0ull);
      }
      if (ok) break;
      __builtin_amdgcn_s_sleep(1);
    }
#pragma unroll
    for (int j = 0; j < 8; ++j) {
      unsigned cc = (tid & 15) * 8 + j;    // 16B chunk index within row
      unsigned pos = cc ^ (srow & 7) ^ ((cc >> 3) & 7);   // dual-XOR swizzle
      *(f16x8*)&Hl[srow * 1024 + (pos << 3)] = st[j];
    }
    __syncthreads();   // h-tile ready for all waves

    // ---- gates = h_{t-1}[m-tile] @ Whh_slice[n-tile]^T (A from Hl) ----
    f32x4 acc0 = {0.f, 0.f, 0.f, 0.f};
    f32x4 acc1 = {0.f, 0.f, 0.f, 0.f};
#pragma unroll
    for (unsigned ks = 0; ks < 16; ks += 2) {
      unsigned c0 = ks * 4 + hi, c1 = c0 + 4;
      unsigned p0 = c0 ^ (arow & 7) ^ ((c0 >> 3) & 7);
      unsigned p1 = c1 ^ (arow & 7) ^ ((c1 >> 3) & 7);
      f16x8 a0 = *(const f16x8*)&Hl[arow * 1024 + (p0 << 3)];
      f16x8 a1 = *(const f16x8*)&Hl[arow * 1024 + (p1 << 3)];
      f16x8 b0 = *(const f16x8*)&Wl[rWl * 512 + ((c0 ^ (rWl & 7)) << 3)];
      f16x8 b1 = *(const f16x8*)&Wl[rWl * 512 + ((c1 ^ (rWl & 7)) << 3)];
      acc0 = __builtin_amdgcn_mfma_f32_16x16x32_f16(a0, b0, acc0, 0, 0, 0);
      acc1 = __builtin_amdgcn_mfma_f32_16x16x32_f16(a1, b1, acc1, 0, 0, 0);
    }
#pragma unroll
    for (unsigned ks = 16; ks < 32; ks += 2) {
      unsigned c0 = ks * 4 + hi, c1 = c0 + 4;
      unsigned p0 = c0 ^ (arow & 7) ^ ((c0 >> 3) & 7);
      unsigned p1 = c1 ^ (arow & 7) ^ ((c1 >> 3) & 7);
      f16x8 a0 = *(const f16x8*)&Hl[arow * 1024 + (p0 << 3)];
      f16x8 a1 = *(const f16x8*)&Hl[arow * 1024 + (p1 << 3)];
      acc0 = __builtin_amdgcn_mfma_f32_16x16x32_f16(a0, breg[ks - 16], acc0, 0, 0, 0);
      acc1 = __builtin_amdgcn_mfma_f32_16x16x32_f16(a1, breg[ks - 15], acc1, 0, 0, 0);
    }
    __syncthreads();   // all Hl reads done -> next iteration may overwrite

    // ---- activations + state update (quad holds i,f,g,o of one (d, b-set)) ----
    float hv[4];
#pragma unroll
    for (int z = 0; z < 4; ++z) {
      float v = acc0[z] + acc1[z] + xv[z];
      float a = (q == 2) ? fast_tanh(v) : fast_sigmoid(v);
      float A1 = __shfl_xor(a, 1, 64);
      float A2 = __shfl_xor(a, 2, 64);
      float A3 = __shfl_xor(a, 3, 64);
      float iact = (q == 0) ? a  : (q == 1) ? A1 : (q == 2) ? A2 : A3;
      float fact = (q == 0) ? A1 : (q == 1) ? a  : (q == 2) ? A3 : A2;
      float gact = (q == 0) ? A2 : (q == 1) ? A3 : (q == 2) ? a  : A1;
      float oact = (q == 0) ? A3 : (q == 1) ? A2 : (q == 2) ? A1 : a;
      float cn = fact * c_st[z] + iact * gact;
      c_st[z] = cn;
      hv[z] = oact * fast_tanh(cn);
    }
    // ---- pack h(d0..d0+3) per batch into 8B, store via sc1 (16/wave) ----
    unsigned sb = lane & 48;   // hi*16
    float g[4][4];
#pragma unroll
    for (int j = 0; j < 4; ++j) {
      g[j][0] = __shfl(hv[0], (int)(sb | (j << 2)), 64);
      g[j][1] = __shfl(hv[1], (int)(sb | (j << 2)), 64);
      g[j][2] = __shfl(hv[2], (int)(sb | (j << 2)), 64);
      g[j][3] = __shfl(hv[3], (int)(sb | (j << 2)), 64);
    }
    if ((rl & 3) == 0) {
      unsigned zb = rl >> 2;   // this lane stores batch bB+zb
      union { f16 h4[4]; u64 u; } pk;
#pragma unroll
      for (int j = 0; j < 4; ++j) {
        float tv = (zb == 0) ? g[j][0] : (zb == 1) ? g[j][1]
                 : (zb == 2) ? g[j][2] : g[j][3];
        pk.h4[j] = (f16)tv;
      }
      f16* hw = h_all + ((size_t)t * B_ + bB + zb) * H_ + d0;
      llc_st64(hw, pk.u);
    }
    // no release: stores drain under the next step's spin (vmcnt(0) there)
  }
}

// ---------------- logits: out[b][t][c] = relu(h[t+1]) . W_score[c] ----------------

__global__ __launch_bounds__(256) void k_logits(
    const f16* __restrict__ h_all, const float* __restrict__ wsc,
    float* __restrict__ out) {
  __shared__ float Ws[2048];
  unsigned tid = threadIdx.x;
  for (unsigned i = tid; i < 512; i += 256) ((float4*)Ws)[i] = ((const float4*)wsc)[i];
  __syncthreads();
  unsigned w = tid >> 6, lane = tid & 63;
  unsigned base = blockIdx.x * 64 + w * 16;
  for (unsigned i = 0; i < 16; ++i) {
    unsigned idx = base + i;                // 0..65535
    unsigned tt = idx >> 5, b = idx & 31;
    const f16* hp = h_all + ((size_t)(idx + 32)) * H_ + lane * 16;
    f16x8 ha = *(const f16x8*)hp;
    f16x8 hb = *(const f16x8*)(hp + 8);
    float s0 = 0.f, s1 = 0.f;
#pragma unroll
    for (int z = 0; z < 8; ++z) {
      float hv = fmaxf((float)ha[z], 0.f);
      s0 += hv * Ws[lane * 16 + z];
      s1 += hv * Ws[1024 + lane * 16 + z];
    }
#pragma unroll
    for (int z = 0; z < 8; ++z) {
      float hv = fmaxf((float)hb[z], 0.f);
      s0 += hv * Ws[lane * 16 + 8 + z];
      s1 += hv * Ws[1024 + lane * 16 + 8 + z];
    }
#pragma unroll
    for (int off = 32; off; off >>= 1) {
      s0 += __shfl_xor(s0, off, 64);
      s1 += __shfl_xor(s1, off, 64);
    }
    if (lane == 0) {
      out[((size_t)b * T_ + tt) * 2 + 0] = s0;
      out[((size_t)b * T_ + tt) * 2 + 1] = s1;
    }
  }
}

// ---------------- launch ----------------

extern "C" void kernel_launch(void* const* d_in, const int* in_sizes, int n_in,
                              void* d_out, int out_size, void* d_ws, size_t ws_size,
                              hipStream_t stream) {
  const int*   seq = (const int*)d_in[0];
  const float* emb = (const float*)d_in[1];
  const float* wih = (const float*)d_in[2];
  const float* whh = (const float*)d_in[3];
  const float* bih = (const float*)d_in[4];
  const float* bhh = (const float*)d_in[5];
  const float* wsc = (const float*)d_in[6];
  float* out = (float*)d_out;
  char* ws = (char*)d_ws;

  const size_t NEED = 790874112ull;
  if (ws_size < NEED) return;  // workspace too small: output stays zero (detectable)

  f16*   emb16 = (f16*)(ws);
  f16*   wih16 = (f16*)(ws + 102926336ull);
  f16*   wr16  = (f16*)(ws + 111314944ull);
  float* bias  = (float*)(ws + 119703552ull);
  f16*   xg    = (f16*)(ws + 119719936ull);
  f16*   h_all = (f16*)(ws + 656590848ull);

  hipMemsetAsync(h_all, 0, (size_t)B_ * H_ * 2, stream);                // h_0 = 0
  hipMemsetAsync((char*)h_all + (size_t)B_ * H_ * 2, 0xFF,
                 (size_t)T_ * B_ * H_ * 2, stream);                     // poison h_1..h_T

  k_cvt_f16<<<50257, 256, 0, stream>>>(emb, emb16, 12865792L);
  k_cvt_f16<<<4096, 256, 0, stream>>>(wih, wih16, 1048576L);
  k_whh_reorder<<<2048, 256, 0, stream>>>(whh, wr16);
  k_bias<<<16, 256, 0, stream>>>(bih, bhh, bias);

  k_gemm_xg<<<16384, 256, 0, stream>>>(seq, emb16, wih16, bias, xg);
  k_lstm<<<64, 512, 0, stream>>>(xg, wr16, h_all);
  k_logits<<<1024, 256, 0, stream>>>(h_all, wsc, out);
}

// Round 14
// 16464.169 us; speedup vs baseline: 2.2857x; 1.2199x over previous
//
#include <hip/hip_runtime.h>
#include <hip/hip_bf16.h>

// LSTM classifier: emb gather -> input GEMM (fp16 MFMA) -> persistent
// recurrence with DATA-CARRIED sync (poison-tagged h words) -> logits.
// R14 = R11 protocol, restructured as TWO batch-phases per step (A: b0-15,
// B: b16-31) so each stream's visibility latency S hides under the other
// stream's compute. MFMA: single M=16 tile per phase; the wave m-split
// becomes a K-split (mt0: k<512 from LDS Wl, mt1: k>=512 from VGPR breg)
// with partial sums combined through a small LDS exchange.
//
// Workspace layout (bytes):
//   emb16   @ 0          : 50257*1024*2 = 102,926,336
//   wih16   @ 102926336  : 4096*1024*2  =   8,388,608
//   wr16    @ 111314944  : 4096*1024*2  =   8,388,608   (W_hh reordered, fp16)
//   bias    @ 119703552  : 4096*4       =      16,384   (b_ih + b_hh, f32)
//   xg      @ 119719936  : 65536*4096*2 = 536,870,912   (x_gates fp16, [t][b][R'])
//   h_all   @ 656590848  : 2049*32*1024*2 = 134,283,264 (h; t>=1 poisoned 0xFFFF per launch)
//   total: 790,874,112

typedef _Float16 f16;
typedef _Float16 f16x8 __attribute__((ext_vector_type(8)));
typedef _Float16 f16x4 __attribute__((ext_vector_type(4)));
typedef float    f32x4 __attribute__((ext_vector_type(4)));
typedef unsigned long long u64;

#define B_    32
#define T_    2048
#define H_    1024
#define G4_   4096

__device__ __forceinline__ void gl_lds16(const void* g, void* l) {
  __builtin_amdgcn_global_load_lds(
      (const __attribute__((address_space(1))) void*)g,
      (__attribute__((address_space(3))) void*)l, 16, 0, 0);
}

// agent-scope (LLC) 8B store — write-through past the non-coherent XCD L2s
__device__ __forceinline__ void llc_st64(void* p, u64 v) {
  __hip_atomic_store((u64*)p, v, __ATOMIC_RELAXED, __HIP_MEMORY_SCOPE_AGENT);
}

// fast activations: v_exp_f32 + v_rcp_f32 (no libm branches on critical path)
__device__ __forceinline__ float fast_sigmoid(float v) {
  return __builtin_amdgcn_rcpf(1.f + __expf(-v));
}
__device__ __forceinline__ float fast_tanh(float v) {
  return 1.f - 2.f * __builtin_amdgcn_rcpf(1.f + __expf(2.f * v));
}

// ---------------- conversions ----------------

__global__ void k_cvt_f16(const float* __restrict__ in, f16* __restrict__ out, long n4) {
  long i = (long)blockIdx.x * blockDim.x + threadIdx.x;
  if (i >= n4) return;
  float4 v = ((const float4*)in)[i];
  f16x4 o; o[0] = (f16)v.x; o[1] = (f16)v.y; o[2] = (f16)v.z; o[3] = (f16)v.w;
  *(f16x4*)(out + i * 4) = o;
}

// W_hh row (q*1024 + j) -> wr16 row R' = (j>>4)*64 + (j&15)*4 + q; fp16.
// => WG wid owns contiguous rows [wid*64, wid*64+64) = h-dims [wid*16, +16).
__global__ void k_whh_reorder(const float* __restrict__ whh, f16* __restrict__ wr) {
  unsigned i = blockIdx.x * blockDim.x + threadIdx.x;   // one thread per 8 elems
  unsigned e0 = i * 8;
  unsigned R = e0 >> 10, k = e0 & 1023;
  unsigned q = R >> 10, j = R & 1023;
  unsigned outR = ((j >> 4) << 6) + ((j & 15) << 2) + q;
  float4 v0 = ((const float4*)whh)[e0 / 4];
  float4 v1 = ((const float4*)whh)[e0 / 4 + 1];
  f16x8 o;
  o[0] = (f16)v0.x; o[1] = (f16)v0.y; o[2] = (f16)v0.z; o[3] = (f16)v0.w;
  o[4] = (f16)v1.x; o[5] = (f16)v1.y; o[6] = (f16)v1.z; o[7] = (f16)v1.w;
  *(f16x8*)&wr[((size_t)outR << 10) + k] = o;
}

__global__ void k_bias(const float* __restrict__ bi, const float* __restrict__ bh,
                       float* __restrict__ bo) {
  unsigned i = blockIdx.x * blockDim.x + threadIdx.x;
  if (i < G4_) bo[i] = bi[i] + bh[i];
}

// ---------------- input GEMM: xg[m][R'(n)] = emb[seq] @ W_ih^T + bias ----------------
// m = t*32 + b (so xg layout is [t][b][R']); 128x128 tile, BK=64, 4 waves.

__global__ __launch_bounds__(256) void k_gemm_xg(
    const int* __restrict__ seq, const f16* __restrict__ emb16,
    const f16* __restrict__ wih16, const float* __restrict__ bias,
    f16* __restrict__ xg) {
  __shared__ f16 As[128 * 64];
  __shared__ f16 Bs[128 * 64];
  const unsigned tid = threadIdx.x;
  const unsigned w = tid >> 6, lane = tid & 63;
  const unsigned bid = blockIdx.x;
  const unsigned tn = bid & 31, tm = bid >> 5;
  const unsigned wm = (w >> 1) * 64, wn = (w & 1) * 64;

  f32x4 zero = {0.f, 0.f, 0.f, 0.f};
  f32x4 acc[4][4];
#pragma unroll
  for (int i = 0; i < 4; ++i)
#pragma unroll
    for (int j = 0; j < 4; ++j) acc[i][j] = zero;

  for (unsigned kk = 0; kk < 16; ++kk) {
    const unsigned k0 = kk * 64;
#pragma unroll
    for (unsigned c = 0; c < 4; ++c) {
      unsigned idx = c * 256 + tid;
      unsigned row = idx >> 3, ch = idx & 7;
      unsigned chs = ch ^ (row & 7);
      unsigned m = tm * 128 + row;
      unsigned t = m >> 5, b = m & 31;
      int e = seq[b * 2048 + t];
      const f16* src = emb16 + ((size_t)e << 10) + k0 + chs * 8;
      gl_lds16(src, (char*)As + c * 4096 + w * 1024);
    }
#pragma unroll
    for (unsigned c = 0; c < 4; ++c) {
      unsigned idx = c * 256 + tid;
      unsigned row = idx >> 3, ch = idx & 7;
      unsigned chs = ch ^ (row & 7);
      unsigned n = tn * 128 + row;
      const f16* src = wih16 + ((size_t)n << 10) + k0 + chs * 8;
      gl_lds16(src, (char*)Bs + c * 4096 + w * 1024);
    }
    __syncthreads();
#pragma unroll
    for (unsigned ks = 0; ks < 2; ++ks) {
      f16x8 af[4], bf[4];
      unsigned kc = ks * 4 + (lane >> 4);
#pragma unroll
      for (unsigned fm = 0; fm < 4; ++fm) {
        unsigned r = wm + fm * 16 + (lane & 15);
        af[fm] = *(const f16x8*)&As[r * 64 + ((kc ^ (r & 7)) << 3)];
      }
#pragma unroll
      for (unsigned fn = 0; fn < 4; ++fn) {
        unsigned r = wn + fn * 16 + (lane & 15);
        bf[fn] = *(const f16x8*)&Bs[r * 64 + ((kc ^ (r & 7)) << 3)];
      }
#pragma unroll
      for (unsigned fm = 0; fm < 4; ++fm)
#pragma unroll
        for (unsigned fn = 0; fn < 4; ++fn)
          acc[fm][fn] = __builtin_amdgcn_mfma_f32_16x16x32_f16(af[fm], bf[fn], acc[fm][fn], 0, 0, 0);
    }
    __syncthreads();
  }
  // epilogue: + bias, fp16 store into gate-interleaved layout R'
#pragma unroll
  for (unsigned fn = 0; fn < 4; ++fn) {
    unsigned n = tn * 128 + wn + fn * 16 + (lane & 15);
    unsigned q = n >> 10, j = n & 1023;
    unsigned Rp = ((j >> 4) << 6) + ((j & 15) << 2) + q;
    float bv = bias[n];
#pragma unroll
    for (unsigned fm = 0; fm < 4; ++fm) {
#pragma unroll
      for (unsigned rg = 0; rg < 4; ++rg) {
        unsigned m = tm * 128 + wm + fm * 16 + (lane >> 4) * 4 + rg;
        xg[(size_t)m * G4_ + Rp] = (f16)(acc[fm][fn][rg] + bv);
      }
    }
  }
}

// ---------------- persistent LSTM recurrence, 2-phase data-carried sync ----------------
// 64 WGs x 512 threads. WG wid owns h-dims [wid*16,+16) (64 gate rows).
// Per step t, two phases (s=0: batches 0..15, s=1: 16..31):
//   [spin on own 64B of 16-row slice][stage -> Hl][bar][MFMA K-split][bar]
//   [mt0: combine partials + act + 8B-packed sc1 stores]
// Stream A's store->next-spin gap contains the whole B phase, so the two
// phases share one visibility latency S: per 2 steps ~ S + C.
// MFMA: M=16 (stream batches) x 4 n-tiles x K-split: mt0 waves k<512 (Wl),
// mt1 waves k>=512 (breg); partials via Ps (12KB LDS), guarded by the
// existing barriers. Protocol identical to R11 (8B granules, u64 checks).

__global__ __launch_bounds__(512) void k_lstm(
    const f16* __restrict__ xg, const f16* __restrict__ wr16,
    f16* __restrict__ h_all) {
  __shared__ f16 Wl[64 * 512];       // 64 KB: W_hh slice, k < 512
  __shared__ f16 Hl[16 * 1024];      // 32 KB: 16-row h staging tile (shared A/B)
  __shared__ float Ps[4 * 64 * 12];  // 12 KB: partial sums (48B/lane stride)
  const unsigned tid = threadIdx.x;
  const unsigned w = tid >> 6, lane = tid & 63;
  const unsigned wid = blockIdx.x;          // 0..63
  const unsigned mt = w >> 2, nt = w & 3;

  // stage W k<512 (64 rows x 64 16B-chunks), source-swizzled, linear LDS dest
  for (unsigned c = 0; c < 8; ++c) {
    unsigned idx = c * 512 + tid;
    unsigned row = idx >> 6, ch = idx & 63;
    unsigned chs = ch ^ (row & 7);
    const f16* src = wr16 + (((size_t)wid * 64 + row) << 10) + chs * 8;
    gl_lds16(src, (char*)Wl + c * 8192 + w * 1024);
  }

  const unsigned rl = lane & 15, hi = lane >> 4;
  const unsigned q = rl & 3;                 // gate id within quad
  const unsigned rWl = nt * 16 + rl;         // W row 0..63 within slice
  const unsigned d0 = wid * 16 + nt * 4;     // first h-dim of this wave's quads

  // breg: k in [512,1024) for mt1 waves only (asm-pinned; R3 lesson)
  f16x8 breg[16];
  if (mt == 1) {
    const f16* wp = wr16 + (((size_t)wid * 64 + rWl) << 10) + 512 + hi * 8;
#pragma unroll
    for (int j = 0; j < 16; ++j) {
      asm volatile("global_load_dwordx4 %0, %1, off\n\ts_waitcnt vmcnt(0)"
                   : "=v"(breg[j]) : "v"(wp + j * 32) : "memory");
    }
  }
  __syncthreads();   // Wl staged + breg loaded

  // staging: 16 rows x 128 chunks(16B); thread owns row tid>>5, 4 chunks
  const unsigned srow = tid >> 5;            // 0..15 (batch within stream)
  const unsigned scg = (tid & 31) * 4;       // first chunk index (0..124)
  float cA[4] = {0.f, 0.f, 0.f, 0.f};
  float cB[4] = {0.f, 0.f, 0.f, 0.f};

  for (unsigned t = 1; t <= (unsigned)T_; ++t) {
#pragma unroll
    for (int s = 0; s < 2; ++s) {
      const unsigned sb16 = s * 16;
      // xv loads (mt0 only; issued before the spin, drain under it)
      float xv[4] = {0.f, 0.f, 0.f, 0.f};
      if (mt == 0) {
        const f16* xp = xg + ((size_t)(t - 1) * B_ + sb16 + hi * 4) * G4_ + wid * 64 + rWl;
#pragma unroll
        for (int z = 0; z < 4; ++z) xv[z] = (float)xp[(size_t)z * G4_];
      }
      // ---- spin on own 64B of h_{t-1}[sb16+srow] (R11 protocol) ----
      const f16* gp = h_all + ((size_t)(t - 1) * B_ + sb16 + srow) * H_ + scg * 8;
      f16x8 st[4];
      while (true) {
#pragma unroll
        for (int j = 0; j < 4; ++j)
          asm volatile("global_load_dwordx4 %0, %1, off sc0 sc1"
                       : "=v"(st[j]) : "v"(gp + j * 8));
        asm volatile("s_waitcnt vmcnt(0)" ::: "memory");
        __builtin_amdgcn_sched_barrier(0);   // rule #18
        bool ok = true;
#pragma unroll
        for (int j = 0; j < 4; ++j) {
          union { f16x8 v; u64 u[2]; } uu; uu.v = st[j];
          ok = ok && (uu.u[0] != ~0ull) && (uu.u[1] != ~0ull);
        }
        if (ok) break;
        __builtin_amdgcn_s_sleep(1);
      }
#pragma unroll
      for (int j = 0; j < 4; ++j) {
        unsigned cc = scg + j;
        unsigned pos = cc ^ (srow & 7) ^ ((cc >> 3) & 7);   // dual-XOR swizzle
        *(f16x8*)&Hl[srow * 1024 + (pos << 3)] = st[j];
      }
      __syncthreads();   // h-tile staged

      // ---- MFMA K-split: M=16 batches x 16 W rows per n-tile ----
      f32x4 acc0 = {0.f, 0.f, 0.f, 0.f};
      f32x4 acc1 = {0.f, 0.f, 0.f, 0.f};
      if (mt == 0) {
#pragma unroll
        for (unsigned ks = 0; ks < 16; ks += 2) {
          unsigned c0 = ks * 4 + hi, c1 = c0 + 4;
          unsigned p0 = c0 ^ (rl & 7) ^ ((c0 >> 3) & 7);
          unsigned p1 = c1 ^ (rl & 7) ^ ((c1 >> 3) & 7);
          f16x8 a0 = *(const f16x8*)&Hl[rl * 1024 + (p0 << 3)];
          f16x8 a1 = *(const f16x8*)&Hl[rl * 1024 + (p1 << 3)];
          f16x8 b0 = *(const f16x8*)&Wl[rWl * 512 + ((c0 ^ (rWl & 7)) << 3)];
          f16x8 b1 = *(const f16x8*)&Wl[rWl * 512 + ((c1 ^ (rWl & 7)) << 3)];
          acc0 = __builtin_amdgcn_mfma_f32_16x16x32_f16(a0, b0, acc0, 0, 0, 0);
          acc1 = __builtin_amdgcn_mfma_f32_16x16x32_f16(a1, b1, acc1, 0, 0, 0);
        }
      } else {
#pragma unroll
        for (unsigned ks = 16; ks < 32; ks += 2) {
          unsigned c0 = ks * 4 + hi, c1 = c0 + 4;
          unsigned p0 = c0 ^ (rl & 7) ^ ((c0 >> 3) & 7);
          unsigned p1 = c1 ^ (rl & 7) ^ ((c1 >> 3) & 7);
          f16x8 a0 = *(const f16x8*)&Hl[rl * 1024 + (p0 << 3)];
          f16x8 a1 = *(const f16x8*)&Hl[rl * 1024 + (p1 << 3)];
          acc0 = __builtin_amdgcn_mfma_f32_16x16x32_f16(a0, breg[ks - 16], acc0, 0, 0, 0);
          acc1 = __builtin_amdgcn_mfma_f32_16x16x32_f16(a1, breg[ks - 15], acc1, 0, 0, 0);
        }
        // publish k-high partials
        float* pp = &Ps[((unsigned)nt * 64 + lane) * 12];
        *(f32x4*)pp = acc0;
        *(f32x4*)(pp + 4) = acc1;
      }
      __syncthreads();   // MFMA + partials done; Hl reads done

      // ---- mt0: combine, activations, 8B-packed h stores ----
      if (mt == 0) {
        const float* pp = &Ps[((unsigned)nt * 64 + lane) * 12];
        f32x4 q0 = *(const f32x4*)pp;
        f32x4 q1 = *(const f32x4*)(pp + 4);
        float hv[4];
#pragma unroll
        for (int z = 0; z < 4; ++z) {
          float v = acc0[z] + acc1[z] + q0[z] + q1[z] + xv[z];
          float a = (q == 2) ? fast_tanh(v) : fast_sigmoid(v);
          float A1 = __shfl_xor(a, 1, 64);
          float A2 = __shfl_xor(a, 2, 64);
          float A3 = __shfl_xor(a, 3, 64);
          float iact = (q == 0) ? a  : (q == 1) ? A1 : (q == 2) ? A2 : A3;
          float fact = (q == 0) ? A1 : (q == 1) ? a  : (q == 2) ? A3 : A2;
          float gact = (q == 0) ? A2 : (q == 1) ? A3 : (q == 2) ? a  : A1;
          float oact = (q == 0) ? A3 : (q == 1) ? A2 : (q == 2) ? A1 : a;
          float* cs = (s == 0) ? cA : cB;   // s is compile-time (unrolled)
          float cn = fact * cs[z] + iact * gact;
          cs[z] = cn;
          hv[z] = oact * fast_tanh(cn);
        }
        unsigned sb = lane & 48;   // hi*16
        float g[4][4];
#pragma unroll
        for (int j = 0; j < 4; ++j) {
          g[j][0] = __shfl(hv[0], (int)(sb | (j << 2)), 64);
          g[j][1] = __shfl(hv[1], (int)(sb | (j << 2)), 64);
          g[j][2] = __shfl(hv[2], (int)(sb | (j << 2)), 64);
          g[j][3] = __shfl(hv[3], (int)(sb | (j << 2)), 64);
        }
        if ((rl & 3) == 0) {
          unsigned zb = rl >> 2;   // batch sb16 + hi*4 + zb
          union { f16 h4[4]; u64 u; } pk;
#pragma unroll
          for (int j = 0; j < 4; ++j) {
            float tv = (zb == 0) ? g[j][0] : (zb == 1) ? g[j][1]
                     : (zb == 2) ? g[j][2] : g[j][3];
            pk.h4[j] = (f16)tv;
          }
          f16* hw = h_all + ((size_t)t * B_ + sb16 + hi * 4 + zb) * H_ + d0;
          llc_st64(hw, pk.u);
        }
      }
      // stores drain under the next phase's spin vmcnt(0)
    }
  }
}

// ---------------- logits: out[b][t][c] = relu(h[t+1]) . W_score[c] ----------------

__global__ __launch_bounds__(256) void k_logits(
    const f16* __restrict__ h_all, const float* __restrict__ wsc,
    float* __restrict__ out) {
  __shared__ float Ws[2048];
  unsigned tid = threadIdx.x;
  for (unsigned i = tid; i < 512; i += 256) ((float4*)Ws)[i] = ((const float4*)wsc)[i];
  __syncthreads();
  unsigned w = tid >> 6, lane = tid & 63;
  unsigned base = blockIdx.x * 64 + w * 16;
  for (unsigned i = 0; i < 16; ++i) {
    unsigned idx = base + i;                // 0..65535
    unsigned tt = idx >> 5, b = idx & 31;
    const f16* hp = h_all + ((size_t)(idx + 32)) * H_ + lane * 16;
    f16x8 ha = *(const f16x8*)hp;
    f16x8 hb = *(const f16x8*)(hp + 8);
    float s0 = 0.f, s1 = 0.f;
#pragma unroll
    for (int z = 0; z < 8; ++z) {
      float hv = fmaxf((float)ha[z], 0.f);
      s0 += hv * Ws[lane * 16 + z];
      s1 += hv * Ws[1024 + lane * 16 + z];
    }
#pragma unroll
    for (int z = 0; z < 8; ++z) {
      float hv = fmaxf((float)hb[z], 0.f);
      s0 += hv * Ws[lane * 16 + 8 + z];
      s1 += hv * Ws[1024 + lane * 16 + 8 + z];
    }
#pragma unroll
    for (int off = 32; off; off >>= 1) {
      s0 += __shfl_xor(s0, off, 64);
      s1 += __shfl_xor(s1, off, 64);
    }
    if (lane == 0) {
      out[((size_t)b * T_ + tt) * 2 + 0] = s0;
      out[((size_t)b * T_ + tt) * 2 + 1] = s1;
    }
  }
}

// ---------------- launch ----------------

extern "C" void kernel_launch(void* const* d_in, const int* in_sizes, int n_in,
                              void* d_out, int out_size, void* d_ws, size_t ws_size,
                              hipStream_t stream) {
  const int*   seq = (const int*)d_in[0];
  const float* emb = (const float*)d_in[1];
  const float* wih = (const float*)d_in[2];
  const float* whh = (const float*)d_in[3];
  const float* bih = (const float*)d_in[4];
  const float* bhh = (const float*)d_in[5];
  const float* wsc = (const float*)d_in[6];
  float* out = (float*)d_out;
  char* ws = (char*)d_ws;

  const size_t NEED = 790874112ull;
  if (ws_size < NEED) return;  // workspace too small: output stays zero (detectable)

  f16*   emb16 = (f16*)(ws);
  f16*   wih16 = (f16*)(ws + 102926336ull);
  f16*   wr16  = (f16*)(ws + 111314944ull);
  float* bias  = (float*)(ws + 119703552ull);
  f16*   xg    = (f16*)(ws + 119719936ull);
  f16*   h_all = (f16*)(ws + 656590848ull);

  hipMemsetAsync(h_all, 0, (size_t)B_ * H_ * 2, stream);                // h_0 = 0
  hipMemsetAsync((char*)h_all + (size_t)B_ * H_ * 2, 0xFF,
                 (size_t)T_ * B_ * H_ * 2, stream);                     // poison h_1..h_T

  k_cvt_f16<<<50257, 256, 0, stream>>>(emb, emb16, 12865792L);
  k_cvt_f16<<<4096, 256, 0, stream>>>(wih, wih16, 1048576L);
  k_whh_reorder<<<2048, 256, 0, stream>>>(whh, wr16);
  k_bias<<<16, 256, 0, stream>>>(bih, bhh, bias);

  k_gemm_xg<<<16384, 256, 0, stream>>>(seq, emb16, wih16, bias, xg);
  k_lstm<<<64, 512, 0, stream>>>(xg, wr16, h_all);
  k_logits<<<1024, 256, 0, stream>>>(h_all, wsc, out);
}

// Round 15
// 15902.933 us; speedup vs baseline: 2.3664x; 1.0353x over previous
//
#include <hip/hip_runtime.h>
#include <hip/hip_bf16.h>

// LSTM classifier: emb gather -> input GEMM (fp16 MFMA) -> persistent
// recurrence with DATA-CARRIED sync (poison-tagged h words) -> logits.
// R15 = R14 + two register-free (global_load_lds) prefetches issued right
// after each phase's spin: (1) xg staged one step ahead into LDS Xl (the xv
// HBM loads were draining inside the spin's vmcnt(0)); (2) LLC-warming of
// the next step's h slice into a dump buffer (poison lines get evicted to
// HBM by xg streaming; first sweep paid ~1us HBM latency on the spin path).
//
// Workspace layout (bytes):
//   emb16   @ 0          : 50257*1024*2 = 102,926,336
//   wih16   @ 102926336  : 4096*1024*2  =   8,388,608
//   wr16    @ 111314944  : 4096*1024*2  =   8,388,608   (W_hh reordered, fp16)
//   bias    @ 119703552  : 4096*4       =      16,384   (b_ih + b_hh, f32)
//   xg      @ 119719936  : 65536*4096*2 = 536,870,912   (x_gates fp16, [t][b][R'])
//   h_all   @ 656590848  : 2049*32*1024*2 = 134,283,264 (h; t>=1 poisoned 0xFFFF per launch)
//   total: 790,874,112

typedef _Float16 f16;
typedef _Float16 f16x8 __attribute__((ext_vector_type(8)));
typedef _Float16 f16x4 __attribute__((ext_vector_type(4)));
typedef float    f32x4 __attribute__((ext_vector_type(4)));
typedef unsigned long long u64;

#define B_    32
#define T_    2048
#define H_    1024
#define G4_   4096

__device__ __forceinline__ void gl_lds16(const void* g, void* l) {
  __builtin_amdgcn_global_load_lds(
      (const __attribute__((address_space(1))) void*)g,
      (__attribute__((address_space(3))) void*)l, 16, 0, 0);
}

// agent-scope (LLC) 8B store — write-through past the non-coherent XCD L2s
__device__ __forceinline__ void llc_st64(void* p, u64 v) {
  __hip_atomic_store((u64*)p, v, __ATOMIC_RELAXED, __HIP_MEMORY_SCOPE_AGENT);
}

// fast activations: v_exp_f32 + v_rcp_f32 (no libm branches on critical path)
__device__ __forceinline__ float fast_sigmoid(float v) {
  return __builtin_amdgcn_rcpf(1.f + __expf(-v));
}
__device__ __forceinline__ float fast_tanh(float v) {
  return 1.f - 2.f * __builtin_amdgcn_rcpf(1.f + __expf(2.f * v));
}

// ---------------- conversions ----------------

__global__ void k_cvt_f16(const float* __restrict__ in, f16* __restrict__ out, long n4) {
  long i = (long)blockIdx.x * blockDim.x + threadIdx.x;
  if (i >= n4) return;
  float4 v = ((const float4*)in)[i];
  f16x4 o; o[0] = (f16)v.x; o[1] = (f16)v.y; o[2] = (f16)v.z; o[3] = (f16)v.w;
  *(f16x4*)(out + i * 4) = o;
}

// W_hh row (q*1024 + j) -> wr16 row R' = (j>>4)*64 + (j&15)*4 + q; fp16.
// => WG wid owns contiguous rows [wid*64, wid*64+64) = h-dims [wid*16, +16).
__global__ void k_whh_reorder(const float* __restrict__ whh, f16* __restrict__ wr) {
  unsigned i = blockIdx.x * blockDim.x + threadIdx.x;   // one thread per 8 elems
  unsigned e0 = i * 8;
  unsigned R = e0 >> 10, k = e0 & 1023;
  unsigned q = R >> 10, j = R & 1023;
  unsigned outR = ((j >> 4) << 6) + ((j & 15) << 2) + q;
  float4 v0 = ((const float4*)whh)[e0 / 4];
  float4 v1 = ((const float4*)whh)[e0 / 4 + 1];
  f16x8 o;
  o[0] = (f16)v0.x; o[1] = (f16)v0.y; o[2] = (f16)v0.z; o[3] = (f16)v0.w;
  o[4] = (f16)v1.x; o[5] = (f16)v1.y; o[6] = (f16)v1.z; o[7] = (f16)v1.w;
  *(f16x8*)&wr[((size_t)outR << 10) + k] = o;
}

__global__ void k_bias(const float* __restrict__ bi, const float* __restrict__ bh,
                       float* __restrict__ bo) {
  unsigned i = blockIdx.x * blockDim.x + threadIdx.x;
  if (i < G4_) bo[i] = bi[i] + bh[i];
}

// ---------------- input GEMM: xg[m][R'(n)] = emb[seq] @ W_ih^T + bias ----------------
// m = t*32 + b (so xg layout is [t][b][R']); 128x128 tile, BK=64, 4 waves.

__global__ __launch_bounds__(256) void k_gemm_xg(
    const int* __restrict__ seq, const f16* __restrict__ emb16,
    const f16* __restrict__ wih16, const float* __restrict__ bias,
    f16* __restrict__ xg) {
  __shared__ f16 As[128 * 64];
  __shared__ f16 Bs[128 * 64];
  const unsigned tid = threadIdx.x;
  const unsigned w = tid >> 6, lane = tid & 63;
  const unsigned bid = blockIdx.x;
  const unsigned tn = bid & 31, tm = bid >> 5;
  const unsigned wm = (w >> 1) * 64, wn = (w & 1) * 64;

  f32x4 zero = {0.f, 0.f, 0.f, 0.f};
  f32x4 acc[4][4];
#pragma unroll
  for (int i = 0; i < 4; ++i)
#pragma unroll
    for (int j = 0; j < 4; ++j) acc[i][j] = zero;

  for (unsigned kk = 0; kk < 16; ++kk) {
    const unsigned k0 = kk * 64;
#pragma unroll
    for (unsigned c = 0; c < 4; ++c) {
      unsigned idx = c * 256 + tid;
      unsigned row = idx >> 3, ch = idx & 7;
      unsigned chs = ch ^ (row & 7);
      unsigned m = tm * 128 + row;
      unsigned t = m >> 5, b = m & 31;
      int e = seq[b * 2048 + t];
      const f16* src = emb16 + ((size_t)e << 10) + k0 + chs * 8;
      gl_lds16(src, (char*)As + c * 4096 + w * 1024);
    }
#pragma unroll
    for (unsigned c = 0; c < 4; ++c) {
      unsigned idx = c * 256 + tid;
      unsigned row = idx >> 3, ch = idx & 7;
      unsigned chs = ch ^ (row & 7);
      unsigned n = tn * 128 + row;
      const f16* src = wih16 + ((size_t)n << 10) + k0 + chs * 8;
      gl_lds16(src, (char*)Bs + c * 4096 + w * 1024);
    }
    __syncthreads();
#pragma unroll
    for (unsigned ks = 0; ks < 2; ++ks) {
      f16x8 af[4], bf[4];
      unsigned kc = ks * 4 + (lane >> 4);
#pragma unroll
      for (unsigned fm = 0; fm < 4; ++fm) {
        unsigned r = wm + fm * 16 + (lane & 15);
        af[fm] = *(const f16x8*)&As[r * 64 + ((kc ^ (r & 7)) << 3)];
      }
#pragma unroll
      for (unsigned fn = 0; fn < 4; ++fn) {
        unsigned r = wn + fn * 16 + (lane & 15);
        bf[fn] = *(const f16x8*)&Bs[r * 64 + ((kc ^ (r & 7)) << 3)];
      }
#pragma unroll
      for (unsigned fm = 0; fm < 4; ++fm)
#pragma unroll
        for (unsigned fn = 0; fn < 4; ++fn)
          acc[fm][fn] = __builtin_amdgcn_mfma_f32_16x16x32_f16(af[fm], bf[fn], acc[fm][fn], 0, 0, 0);
    }
    __syncthreads();
  }
  // epilogue: + bias, fp16 store into gate-interleaved layout R'
#pragma unroll
  for (unsigned fn = 0; fn < 4; ++fn) {
    unsigned n = tn * 128 + wn + fn * 16 + (lane & 15);
    unsigned q = n >> 10, j = n & 1023;
    unsigned Rp = ((j >> 4) << 6) + ((j & 15) << 2) + q;
    float bv = bias[n];
#pragma unroll
    for (unsigned fm = 0; fm < 4; ++fm) {
#pragma unroll
      for (unsigned rg = 0; rg < 4; ++rg) {
        unsigned m = tm * 128 + wm + fm * 16 + (lane >> 4) * 4 + rg;
        xg[(size_t)m * G4_ + Rp] = (f16)(acc[fm][fn][rg] + bv);
      }
    }
  }
}

// ---------------- persistent LSTM recurrence, 2-phase data-carried sync ----------------
// 64 WGs x 512 threads. WG wid owns h-dims [wid*16,+16) (64 gate rows).
// Per step t, two phases (s=0: batches 0..15, s=1: 16..31):
//   [spin][issue gl_lds prefetches: h-warm + (s==0) xg->Xl][stage -> Hl][bar]
//   [MFMA K-split][bar][mt0: combine + act + 8B-packed sc1 stores]
// Prefetches are REGISTER-FREE (global_load_lds) -> no liveness hazard
// (the R12/R13 failure class). xv is read from LDS Xl after the barrier;
// nothing with HBM latency drains inside the spin's vmcnt(0) anymore.

__global__ __launch_bounds__(512) void k_lstm(
    const f16* __restrict__ xg, const f16* __restrict__ wr16,
    f16* __restrict__ h_all) {
  __shared__ f16 Wl[64 * 512];       // 64 KB: W_hh slice, k < 512
  __shared__ f16 Hl[16 * 1024];      // 32 KB: 16-row h staging tile (shared A/B)
  __shared__ float Ps[4 * 64 * 12];  // 12 KB: partial sums
  __shared__ f16 Xl[2][2048];        //  8 KB: xg stage, double-buffered by step parity
  __shared__ f16 Hw[512];            //  1 KB: LLC-warm dump target (contents unused)
  const unsigned tid = threadIdx.x;
  const unsigned w = tid >> 6, lane = tid & 63;
  const unsigned wid = blockIdx.x;          // 0..63
  const unsigned mt = w >> 2, nt = w & 3;

  // stage W k<512 (64 rows x 64 16B-chunks), source-swizzled, linear LDS dest
  for (unsigned c = 0; c < 8; ++c) {
    unsigned idx = c * 512 + tid;
    unsigned row = idx >> 6, ch = idx & 63;
    unsigned chs = ch ^ (row & 7);
    const f16* src = wr16 + (((size_t)wid * 64 + row) << 10) + chs * 8;
    gl_lds16(src, (char*)Wl + c * 8192 + w * 1024);
  }
  // pre-stage xg[0] (both phases) into Xl[0]
  if (tid < 256) {
    unsigned s_ph = tid >> 7, brow = (tid >> 3) & 15, ch = tid & 7;
    const f16* src = xg + ((size_t)(s_ph * 16 + brow)) * G4_ + wid * 64 + ch * 8;
    gl_lds16(src, (char*)Xl + w * 1024);
  }

  const unsigned rl = lane & 15, hi = lane >> 4;
  const unsigned q = rl & 3;                 // gate id within quad
  const unsigned rWl = nt * 16 + rl;         // W row 0..63 within slice
  const unsigned d0 = wid * 16 + nt * 4;     // first h-dim of this wave's quads

  // breg: k in [512,1024) for mt1 waves only (asm-pinned; R3 lesson)
  f16x8 breg[16];
  if (mt == 1) {
    const f16* wp = wr16 + (((size_t)wid * 64 + rWl) << 10) + 512 + hi * 8;
#pragma unroll
    for (int j = 0; j < 16; ++j) {
      asm volatile("global_load_dwordx4 %0, %1, off\n\ts_waitcnt vmcnt(0)"
                   : "=v"(breg[j]) : "v"(wp + j * 32) : "memory");
    }
  }
  __syncthreads();   // Wl + Xl staged (barrier drains vmcnt), breg loaded

  // staging: 16 rows x 128 chunks(16B); thread owns row tid>>5, 4 chunks
  const unsigned srow = tid >> 5;            // 0..15 (batch within stream)
  const unsigned scg = (tid & 31) * 4;       // first chunk index (0..124)
  float cA[4] = {0.f, 0.f, 0.f, 0.f};
  float cB[4] = {0.f, 0.f, 0.f, 0.f};

  for (unsigned t = 1; t <= (unsigned)T_; ++t) {
#pragma unroll
    for (int s = 0; s < 2; ++s) {
      const unsigned sb16 = s * 16;
      // ---- spin on own 64B of h_{t-1}[sb16+srow] (R11 protocol, unchanged) ----
      const f16* gp = h_all + ((size_t)(t - 1) * B_ + sb16 + srow) * H_ + scg * 8;
      f16x8 st[4];
      while (true) {
#pragma unroll
        for (int j = 0; j < 4; ++j)
          asm volatile("global_load_dwordx4 %0, %1, off sc0 sc1"
                       : "=v"(st[j]) : "v"(gp + j * 8));
        asm volatile("s_waitcnt vmcnt(0)" ::: "memory");
        __builtin_amdgcn_sched_barrier(0);   // rule #18
        bool ok = true;
#pragma unroll
        for (int j = 0; j < 4; ++j) {
          union { f16x8 v; u64 u[2]; } uu; uu.v = st[j];
          ok = ok && (uu.u[0] != ~0ull) && (uu.u[1] != ~0ull);
        }
        if (ok) break;
        __builtin_amdgcn_s_sleep(1);
      }
      // ---- register-free prefetches (drain under later waits, not here) ----
      // (1) LLC-warm next step's same-phase h slice (dump into Hw)
#pragma unroll
      for (int j = 0; j < 4; ++j)
        gl_lds16(gp + (size_t)B_ * H_ + j * 8, (char*)Hw);
      // (2) stage xg[t] (both phases) into Xl[t&1], once per step
      if (s == 0 && t < (unsigned)T_ && tid < 256) {
        unsigned s_ph = tid >> 7, brow = (tid >> 3) & 15, ch = tid & 7;
        const f16* src = xg + ((size_t)t * B_ + s_ph * 16 + brow) * G4_ + wid * 64 + ch * 8;
        gl_lds16(src, (char*)Xl + (t & 1) * 4096 + w * 1024);
      }
      // ---- stage h into dual-XOR swizzled Hl ----
#pragma unroll
      for (int j = 0; j < 4; ++j) {
        unsigned cc = scg + j;
        unsigned pos = cc ^ (srow & 7) ^ ((cc >> 3) & 7);   // dual-XOR swizzle
        *(f16x8*)&Hl[srow * 1024 + (pos << 3)] = st[j];
      }
      __syncthreads();   // h-tile staged

      // xv from Xl (staged one step ago; LDS reads, no VMEM latency)
      float xv[4] = {0.f, 0.f, 0.f, 0.f};
      if (mt == 0) {
        const f16* xl = (const f16*)Xl + ((t - 1) & 1) * 2048 + sb16 * 64;
#pragma unroll
        for (int z = 0; z < 4; ++z)
          xv[z] = (float)xl[(hi * 4 + z) * 64 + rWl];
      }

      // ---- MFMA K-split: M=16 batches x 16 W rows per n-tile ----
      f32x4 acc0 = {0.f, 0.f, 0.f, 0.f};
      f32x4 acc1 = {0.f, 0.f, 0.f, 0.f};
      if (mt == 0) {
#pragma unroll
        for (unsigned ks = 0; ks < 16; ks += 2) {
          unsigned c0 = ks * 4 + hi, c1 = c0 + 4;
          unsigned p0 = c0 ^ (rl & 7) ^ ((c0 >> 3) & 7);
          unsigned p1 = c1 ^ (rl & 7) ^ ((c1 >> 3) & 7);
          f16x8 a0 = *(const f16x8*)&Hl[rl * 1024 + (p0 << 3)];
          f16x8 a1 = *(const f16x8*)&Hl[rl * 1024 + (p1 << 3)];
          f16x8 b0 = *(const f16x8*)&Wl[rWl * 512 + ((c0 ^ (rWl & 7)) << 3)];
          f16x8 b1 = *(const f16x8*)&Wl[rWl * 512 + ((c1 ^ (rWl & 7)) << 3)];
          acc0 = __builtin_amdgcn_mfma_f32_16x16x32_f16(a0, b0, acc0, 0, 0, 0);
          acc1 = __builtin_amdgcn_mfma_f32_16x16x32_f16(a1, b1, acc1, 0, 0, 0);
        }
      } else {
#pragma unroll
        for (unsigned ks = 16; ks < 32; ks += 2) {
          unsigned c0 = ks * 4 + hi, c1 = c0 + 4;
          unsigned p0 = c0 ^ (rl & 7) ^ ((c0 >> 3) & 7);
          unsigned p1 = c1 ^ (rl & 7) ^ ((c1 >> 3) & 7);
          f16x8 a0 = *(const f16x8*)&Hl[rl * 1024 + (p0 << 3)];
          f16x8 a1 = *(const f16x8*)&Hl[rl * 1024 + (p1 << 3)];
          acc0 = __builtin_amdgcn_mfma_f32_16x16x32_f16(a0, breg[ks - 16], acc0, 0, 0, 0);
          acc1 = __builtin_amdgcn_mfma_f32_16x16x32_f16(a1, breg[ks - 15], acc1, 0, 0, 0);
        }
        // publish k-high partials
        float* pp = &Ps[((unsigned)nt * 64 + lane) * 12];
        *(f32x4*)pp = acc0;
        *(f32x4*)(pp + 4) = acc1;
      }
      __syncthreads();   // MFMA + partials done; Hl reads done

      // ---- mt0: combine, activations, 8B-packed h stores ----
      if (mt == 0) {
        const float* pp = &Ps[((unsigned)nt * 64 + lane) * 12];
        f32x4 q0 = *(const f32x4*)pp;
        f32x4 q1 = *(const f32x4*)(pp + 4);
        float hv[4];
#pragma unroll
        for (int z = 0; z < 4; ++z) {
          float v = acc0[z] + acc1[z] + q0[z] + q1[z] + xv[z];
          float a = (q == 2) ? fast_tanh(v) : fast_sigmoid(v);
          float A1 = __shfl_xor(a, 1, 64);
          float A2 = __shfl_xor(a, 2, 64);
          float A3 = __shfl_xor(a, 3, 64);
          float iact = (q == 0) ? a  : (q == 1) ? A1 : (q == 2) ? A2 : A3;
          float fact = (q == 0) ? A1 : (q == 1) ? a  : (q == 2) ? A3 : A2;
          float gact = (q == 0) ? A2 : (q == 1) ? A3 : (q == 2) ? a  : A1;
          float oact = (q == 0) ? A3 : (q == 1) ? A2 : (q == 2) ? A1 : a;
          float* cs = (s == 0) ? cA : cB;   // s is compile-time (unrolled)
          float cn = fact * cs[z] + iact * gact;
          cs[z] = cn;
          hv[z] = oact * fast_tanh(cn);
        }
        unsigned sb = lane & 48;   // hi*16
        float g[4][4];
#pragma unroll
        for (int j = 0; j < 4; ++j) {
          g[j][0] = __shfl(hv[0], (int)(sb | (j << 2)), 64);
          g[j][1] = __shfl(hv[1], (int)(sb | (j << 2)), 64);
          g[j][2] = __shfl(hv[2], (int)(sb | (j << 2)), 64);
          g[j][3] = __shfl(hv[3], (int)(sb | (j << 2)), 64);
        }
        if ((rl & 3) == 0) {
          unsigned zb = rl >> 2;   // batch sb16 + hi*4 + zb
          union { f16 h4[4]; u64 u; } pk;
#pragma unroll
          for (int j = 0; j < 4; ++j) {
            float tv = (zb == 0) ? g[j][0] : (zb == 1) ? g[j][1]
                     : (zb == 2) ? g[j][2] : g[j][3];
            pk.h4[j] = (f16)tv;
          }
          f16* hw_ = h_all + ((size_t)t * B_ + sb16 + hi * 4 + zb) * H_ + d0;
          llc_st64(hw_, pk.u);
        }
      }
      // stores + prefetches drain under the next phase's spin vmcnt(0)
    }
  }
}

// ---------------- logits: out[b][t][c] = relu(h[t+1]) . W_score[c] ----------------

__global__ __launch_bounds__(256) void k_logits(
    const f16* __restrict__ h_all, const float* __restrict__ wsc,
    float* __restrict__ out) {
  __shared__ float Ws[2048];
  unsigned tid = threadIdx.x;
  for (unsigned i = tid; i < 512; i += 256) ((float4*)Ws)[i] = ((const float4*)wsc)[i];
  __syncthreads();
  unsigned w = tid >> 6, lane = tid & 63;
  unsigned base = blockIdx.x * 64 + w * 16;
  for (unsigned i = 0; i < 16; ++i) {
    unsigned idx = base + i;                // 0..65535
    unsigned tt = idx >> 5, b = idx & 31;
    const f16* hp = h_all + ((size_t)(idx + 32)) * H_ + lane * 16;
    f16x8 ha = *(const f16x8*)hp;
    f16x8 hb = *(const f16x8*)(hp + 8);
    float s0 = 0.f, s1 = 0.f;
#pragma unroll
    for (int z = 0; z < 8; ++z) {
      float hv = fmaxf((float)ha[z], 0.f);
      s0 += hv * Ws[lane * 16 + z];
      s1 += hv * Ws[1024 + lane * 16 + z];
    }
#pragma unroll
    for (int z = 0; z < 8; ++z) {
      float hv = fmaxf((float)hb[z], 0.f);
      s0 += hv * Ws[lane * 16 + 8 + z];
      s1 += hv * Ws[1024 + lane * 16 + 8 + z];
    }
#pragma unroll
    for (int off = 32; off; off >>= 1) {
      s0 += __shfl_xor(s0, off, 64);
      s1 += __shfl_xor(s1, off, 64);
    }
    if (lane == 0) {
      out[((size_t)b * T_ + tt) * 2 + 0] = s0;
      out[((size_t)b * T_ + tt) * 2 + 1] = s1;
    }
  }
}

// ---------------- launch ----------------

extern "C" void kernel_launch(void* const* d_in, const int* in_sizes, int n_in,
                              void* d_out, int out_size, void* d_ws, size_t ws_size,
                              hipStream_t stream) {
  const int*   seq = (const int*)d_in[0];
  const float* emb = (const float*)d_in[1];
  const float* wih = (const float*)d_in[2];
  const float* whh = (const float*)d_in[3];
  const float* bih = (const float*)d_in[4];
  const float* bhh = (const float*)d_in[5];
  const float* wsc = (const float*)d_in[6];
  float* out = (float*)d_out;
  char* ws = (char*)d_ws;

  const size_t NEED = 790874112ull;
  if (ws_size < NEED) return;  // workspace too small: output stays zero (detectable)

  f16*   emb16 = (f16*)(ws);
  f16*   wih16 = (f16*)(ws + 102926336ull);
  f16*   wr16  = (f16*)(ws + 111314944ull);
  float* bias  = (float*)(ws + 119703552ull);
  f16*   xg    = (f16*)(ws + 119719936ull);
  f16*   h_all = (f16*)(ws + 656590848ull);

  hipMemsetAsync(h_all, 0, (size_t)B_ * H_ * 2, stream);                // h_0 = 0
  hipMemsetAsync((char*)h_all + (size_t)B_ * H_ * 2, 0xFF,
                 (size_t)T_ * B_ * H_ * 2, stream);                     // poison h_1..h_T

  k_cvt_f16<<<50257, 256, 0, stream>>>(emb, emb16, 12865792L);
  k_cvt_f16<<<4096, 256, 0, stream>>>(wih, wih16, 1048576L);
  k_whh_reorder<<<2048, 256, 0, stream>>>(whh, wr16);
  k_bias<<<16, 256, 0, stream>>>(bih, bhh, bias);

  k_gemm_xg<<<16384, 256, 0, stream>>>(seq, emb16, wih16, bias, xg);
  k_lstm<<<64, 512, 0, stream>>>(xg, wr16, h_all);
  k_logits<<<1024, 256, 0, stream>>>(h_all, wsc, out);
}

// Round 16
// 14485.443 us; speedup vs baseline: 2.5980x; 1.0979x over previous
//
#include <hip/hip_runtime.h>
#include <hip/hip_bf16.h>

// LSTM classifier: emb gather -> input GEMM (fp16 MFMA) -> persistent
// recurrence with DATA-CARRIED sync (poison-tagged h words) -> logits.
// R16 = R14 with the MFMA operand SWAP: compute gates^T = W @ h^T
// (mfma(W_frag, h_frag, acc); identical Wl/Hl reads by A/B layout symmetry).
// Each lane's 4 acc regs = i,f,g,o of ONE (dim,batch): gate combine needs
// ZERO shuffles, xv is one contiguous f16x4, h is one llc_st16 per lane.
// 256 thr (4 waves, full-K per wave: k<512 Wl + k>=512 breg; no K-split/Ps),
// double-buffered Hl -> ONE barrier per phase. Poison check per-u16
// (h stores are 2B; partial-granule visibility handled).
//
// Workspace layout (bytes):
//   emb16   @ 0          : 50257*1024*2 = 102,926,336
//   wih16   @ 102926336  : 4096*1024*2  =   8,388,608
//   wr16    @ 111314944  : 4096*1024*2  =   8,388,608   (W_hh reordered, fp16)
//   bias    @ 119703552  : 4096*4       =      16,384   (b_ih + b_hh, f32)
//   xg      @ 119719936  : 65536*4096*2 = 536,870,912   (x_gates fp16, [t][b][R'])
//   h_all   @ 656590848  : 2049*32*1024*2 = 134,283,264 (h; t>=1 poisoned 0xFFFF per launch)
//   total: 790,874,112

typedef _Float16 f16;
typedef _Float16 f16x8 __attribute__((ext_vector_type(8)));
typedef _Float16 f16x4 __attribute__((ext_vector_type(4)));
typedef float    f32x4 __attribute__((ext_vector_type(4)));
typedef unsigned long long u64;

#define B_    32
#define T_    2048
#define H_    1024
#define G4_   4096

__device__ __forceinline__ void gl_lds16(const void* g, void* l) {
  __builtin_amdgcn_global_load_lds(
      (const __attribute__((address_space(1))) void*)g,
      (__attribute__((address_space(3))) void*)l, 16, 0, 0);
}

// agent-scope (LLC) 2B store — write-through past the non-coherent XCD L2s
__device__ __forceinline__ void llc_st16(void* p, unsigned short v) {
  __hip_atomic_store((unsigned short*)p, v, __ATOMIC_RELAXED, __HIP_MEMORY_SCOPE_AGENT);
}

// fast activations: v_exp_f32 + v_rcp_f32 (no libm branches on critical path)
__device__ __forceinline__ float fast_sigmoid(float v) {
  return __builtin_amdgcn_rcpf(1.f + __expf(-v));
}
__device__ __forceinline__ float fast_tanh(float v) {
  return 1.f - 2.f * __builtin_amdgcn_rcpf(1.f + __expf(2.f * v));
}

// ---------------- conversions ----------------

__global__ void k_cvt_f16(const float* __restrict__ in, f16* __restrict__ out, long n4) {
  long i = (long)blockIdx.x * blockDim.x + threadIdx.x;
  if (i >= n4) return;
  float4 v = ((const float4*)in)[i];
  f16x4 o; o[0] = (f16)v.x; o[1] = (f16)v.y; o[2] = (f16)v.z; o[3] = (f16)v.w;
  *(f16x4*)(out + i * 4) = o;
}

// W_hh row (q*1024 + j) -> wr16 row R' = (j>>4)*64 + (j&15)*4 + q; fp16.
// => WG wid owns contiguous rows [wid*64, wid*64+64) = h-dims [wid*16, +16).
__global__ void k_whh_reorder(const float* __restrict__ whh, f16* __restrict__ wr) {
  unsigned i = blockIdx.x * blockDim.x + threadIdx.x;   // one thread per 8 elems
  unsigned e0 = i * 8;
  unsigned R = e0 >> 10, k = e0 & 1023;
  unsigned q = R >> 10, j = R & 1023;
  unsigned outR = ((j >> 4) << 6) + ((j & 15) << 2) + q;
  float4 v0 = ((const float4*)whh)[e0 / 4];
  float4 v1 = ((const float4*)whh)[e0 / 4 + 1];
  f16x8 o;
  o[0] = (f16)v0.x; o[1] = (f16)v0.y; o[2] = (f16)v0.z; o[3] = (f16)v0.w;
  o[4] = (f16)v1.x; o[5] = (f16)v1.y; o[6] = (f16)v1.z; o[7] = (f16)v1.w;
  *(f16x8*)&wr[((size_t)outR << 10) + k] = o;
}

__global__ void k_bias(const float* __restrict__ bi, const float* __restrict__ bh,
                       float* __restrict__ bo) {
  unsigned i = blockIdx.x * blockDim.x + threadIdx.x;
  if (i < G4_) bo[i] = bi[i] + bh[i];
}

// ---------------- input GEMM: xg[m][R'(n)] = emb[seq] @ W_ih^T + bias ----------------
// m = t*32 + b (so xg layout is [t][b][R']); 128x128 tile, BK=64, 4 waves.

__global__ __launch_bounds__(256) void k_gemm_xg(
    const int* __restrict__ seq, const f16* __restrict__ emb16,
    const f16* __restrict__ wih16, const float* __restrict__ bias,
    f16* __restrict__ xg) {
  __shared__ f16 As[128 * 64];
  __shared__ f16 Bs[128 * 64];
  const unsigned tid = threadIdx.x;
  const unsigned w = tid >> 6, lane = tid & 63;
  const unsigned bid = blockIdx.x;
  const unsigned tn = bid & 31, tm = bid >> 5;
  const unsigned wm = (w >> 1) * 64, wn = (w & 1) * 64;

  f32x4 zero = {0.f, 0.f, 0.f, 0.f};
  f32x4 acc[4][4];
#pragma unroll
  for (int i = 0; i < 4; ++i)
#pragma unroll
    for (int j = 0; j < 4; ++j) acc[i][j] = zero;

  for (unsigned kk = 0; kk < 16; ++kk) {
    const unsigned k0 = kk * 64;
#pragma unroll
    for (unsigned c = 0; c < 4; ++c) {
      unsigned idx = c * 256 + tid;
      unsigned row = idx >> 3, ch = idx & 7;
      unsigned chs = ch ^ (row & 7);
      unsigned m = tm * 128 + row;
      unsigned t = m >> 5, b = m & 31;
      int e = seq[b * 2048 + t];
      const f16* src = emb16 + ((size_t)e << 10) + k0 + chs * 8;
      gl_lds16(src, (char*)As + c * 4096 + w * 1024);
    }
#pragma unroll
    for (unsigned c = 0; c < 4; ++c) {
      unsigned idx = c * 256 + tid;
      unsigned row = idx >> 3, ch = idx & 7;
      unsigned chs = ch ^ (row & 7);
      unsigned n = tn * 128 + row;
      const f16* src = wih16 + ((size_t)n << 10) + k0 + chs * 8;
      gl_lds16(src, (char*)Bs + c * 4096 + w * 1024);
    }
    __syncthreads();
#pragma unroll
    for (unsigned ks = 0; ks < 2; ++ks) {
      f16x8 af[4], bf[4];
      unsigned kc = ks * 4 + (lane >> 4);
#pragma unroll
      for (unsigned fm = 0; fm < 4; ++fm) {
        unsigned r = wm + fm * 16 + (lane & 15);
        af[fm] = *(const f16x8*)&As[r * 64 + ((kc ^ (r & 7)) << 3)];
      }
#pragma unroll
      for (unsigned fn = 0; fn < 4; ++fn) {
        unsigned r = wn + fn * 16 + (lane & 15);
        bf[fn] = *(const f16x8*)&Bs[r * 64 + ((kc ^ (r & 7)) << 3)];
      }
#pragma unroll
      for (unsigned fm = 0; fm < 4; ++fm)
#pragma unroll
        for (unsigned fn = 0; fn < 4; ++fn)
          acc[fm][fn] = __builtin_amdgcn_mfma_f32_16x16x32_f16(af[fm], bf[fn], acc[fm][fn], 0, 0, 0);
    }
    __syncthreads();
  }
  // epilogue: + bias, fp16 store into gate-interleaved layout R'
#pragma unroll
  for (unsigned fn = 0; fn < 4; ++fn) {
    unsigned n = tn * 128 + wn + fn * 16 + (lane & 15);
    unsigned q = n >> 10, j = n & 1023;
    unsigned Rp = ((j >> 4) << 6) + ((j & 15) << 2) + q;
    float bv = bias[n];
#pragma unroll
    for (unsigned fm = 0; fm < 4; ++fm) {
#pragma unroll
      for (unsigned rg = 0; rg < 4; ++rg) {
        unsigned m = tm * 128 + wm + fm * 16 + (lane >> 4) * 4 + rg;
        xg[(size_t)m * G4_ + Rp] = (f16)(acc[fm][fn][rg] + bv);
      }
    }
  }
}

// ---------------- persistent LSTM recurrence, 2-phase, operand-swapped ----------------
// 64 WGs x 256 threads (4 waves = 4 M-tiles of 16 W rows, FULL K per wave:
// k<512 from Wl, k>=512 from per-wave breg). WG wid owns h-dims [wid*16,+16).
// Per step t, two phases (s=0: batches 0..15, s=1: 16..31):
//   [spin per-u16 poison][stage -> Hl[phase&1]][bar][32-MFMA swapped]
//   [act (no shuffles) + llc_st16] -> next phase (spin vmcnt drains store).
// Swapped mfma(W_frag, h_frag, acc): C[row=gate-row, col=batch] => lane
// (rl=batch, hi=dim-within-4) holds acc[z]= gate z of dim wid*16+nt*4+hi.

__global__ __launch_bounds__(256) void k_lstm(
    const f16* __restrict__ xg, const f16* __restrict__ wr16,
    f16* __restrict__ h_all) {
  __shared__ f16 Wl[64 * 512];       // 64 KB: W_hh slice, k < 512
  __shared__ f16 Hl[2][16 * 1024];   // 64 KB: h staging, double-buffered by phase
  const unsigned tid = threadIdx.x;
  const unsigned nt = tid >> 6, lane = tid & 63;   // 4 waves = 4 M-tiles
  const unsigned wid = blockIdx.x;                 // 0..63
  const unsigned rl = lane & 15, hi = lane >> 4;

  // stage W k<512 (64 rows x 64 16B-chunks), source-swizzled, linear LDS dest
  for (unsigned c = 0; c < 16; ++c) {
    unsigned idx = c * 256 + tid;
    unsigned row = idx >> 6, ch = idx & 63;
    unsigned chs = ch ^ (row & 7);
    const f16* src = wr16 + (((size_t)wid * 64 + row) << 10) + chs * 8;
    gl_lds16(src, (char*)Wl + c * 4096 + nt * 1024);
  }

  const unsigned rWl = nt * 16 + rl;         // W row 0..63 within slice
  const unsigned dd = wid * 16 + nt * 4 + hi; // this lane's h-dim

  // breg: k in [512,1024) for this wave's own rows (asm-pinned; R3 lesson)
  f16x8 breg[16];
  {
    const f16* wp = wr16 + (((size_t)wid * 64 + rWl) << 10) + 512 + hi * 8;
#pragma unroll
    for (int j = 0; j < 16; ++j) {
      asm volatile("global_load_dwordx4 %0, %1, off\n\ts_waitcnt vmcnt(0)"
                   : "=v"(breg[j]) : "v"(wp + j * 32) : "memory");
    }
  }
  __syncthreads();   // Wl staged (barrier drains lgkm/vm) + breg loaded

  // staging: 16 rows x 128 chunks(16B); thread owns row tid>>4, 8 chunks
  const unsigned srow = tid >> 4;            // 0..15 (batch within stream)
  const unsigned scg = (tid & 15) * 8;       // first chunk index
  float cA = 0.f, cB = 0.f;

  for (unsigned t = 1; t <= (unsigned)T_; ++t) {
#pragma unroll
    for (int s = 0; s < 2; ++s) {
      const unsigned sb16 = s * 16;
      const unsigned pb = ((t - 1) * 2 + s) & 1;   // Hl phase buffer
      // xv: the 4 gate pre-activations for (dd, batch sb16+rl) — contiguous
      f16x4 xv4 = *(const f16x4*)(xg + ((size_t)(t - 1) * B_ + sb16 + rl) * G4_
                                  + wid * 64 + (nt * 4 + hi) * 4);
      // ---- spin on own 128B of h_{t-1}[sb16+srow]; per-u16 poison check ----
      const f16* gp = h_all + ((size_t)(t - 1) * B_ + sb16 + srow) * H_ + scg * 8;
      f16x8 st[8];
      while (true) {
#pragma unroll
        for (int j = 0; j < 8; ++j)
          asm volatile("global_load_dwordx4 %0, %1, off sc0 sc1"
                       : "=v"(st[j]) : "v"(gp + j * 8));
        asm volatile("s_waitcnt vmcnt(0)" ::: "memory");
        __builtin_amdgcn_sched_barrier(0);   // rule #18
        bool ok = true;
#pragma unroll
        for (int j = 0; j < 8; ++j) {
          union { f16x8 v; unsigned u[4]; } uu; uu.v = st[j];
#pragma unroll
          for (int k2 = 0; k2 < 4; ++k2) {
            unsigned wv = uu.u[k2];
            ok = ok && ((wv & 0xFFFFu) != 0xFFFFu) && ((wv >> 16) != 0xFFFFu);
          }
        }
        if (ok) break;
        __builtin_amdgcn_s_sleep(1);
      }
      // ---- stage into dual-XOR swizzled Hl[pb] ----
#pragma unroll
      for (int j = 0; j < 8; ++j) {
        unsigned cc = scg + j;
        unsigned pos = cc ^ (srow & 7) ^ ((cc >> 3) & 7);   // dual-XOR swizzle
        *(f16x8*)&Hl[pb][srow * 1024 + (pos << 3)] = st[j];
      }
      __syncthreads();   // h-tile staged (drains lgkm: st[] safe to reuse)

      // ---- gates^T = W rows @ h^T : swapped operands, full K per wave ----
      f32x4 acc0 = {0.f, 0.f, 0.f, 0.f};
      f32x4 acc1 = {0.f, 0.f, 0.f, 0.f};
#pragma unroll
      for (unsigned ks = 0; ks < 16; ks += 2) {
        unsigned c0 = ks * 4 + hi, c1 = c0 + 4;
        unsigned p0 = c0 ^ (rl & 7) ^ ((c0 >> 3) & 7);
        unsigned p1 = c1 ^ (rl & 7) ^ ((c1 >> 3) & 7);
        f16x8 h0 = *(const f16x8*)&Hl[pb][rl * 1024 + (p0 << 3)];
        f16x8 h1 = *(const f16x8*)&Hl[pb][rl * 1024 + (p1 << 3)];
        f16x8 w0 = *(const f16x8*)&Wl[rWl * 512 + ((c0 ^ (rWl & 7)) << 3)];
        f16x8 w1 = *(const f16x8*)&Wl[rWl * 512 + ((c1 ^ (rWl & 7)) << 3)];
        acc0 = __builtin_amdgcn_mfma_f32_16x16x32_f16(w0, h0, acc0, 0, 0, 0);
        acc1 = __builtin_amdgcn_mfma_f32_16x16x32_f16(w1, h1, acc1, 0, 0, 0);
      }
#pragma unroll
      for (unsigned ks = 16; ks < 32; ks += 2) {
        unsigned c0 = ks * 4 + hi, c1 = c0 + 4;
        unsigned p0 = c0 ^ (rl & 7) ^ ((c0 >> 3) & 7);
        unsigned p1 = c1 ^ (rl & 7) ^ ((c1 >> 3) & 7);
        f16x8 h0 = *(const f16x8*)&Hl[pb][rl * 1024 + (p0 << 3)];
        f16x8 h1 = *(const f16x8*)&Hl[pb][rl * 1024 + (p1 << 3)];
        acc0 = __builtin_amdgcn_mfma_f32_16x16x32_f16(breg[ks - 16], h0, acc0, 0, 0, 0);
        acc1 = __builtin_amdgcn_mfma_f32_16x16x32_f16(breg[ks - 15], h1, acc1, 0, 0, 0);
      }
      // ---- activations: lane-local i,f,g,o (NO shuffles) + 2B h store ----
      {
        float gi = acc0[0] + acc1[0] + (float)xv4[0];
        float gf = acc0[1] + acc1[1] + (float)xv4[1];
        float gg = acc0[2] + acc1[2] + (float)xv4[2];
        float go = acc0[3] + acc1[3] + (float)xv4[3];
        float i_ = fast_sigmoid(gi);
        float f_ = fast_sigmoid(gf);
        float g_ = fast_tanh(gg);
        float o_ = fast_sigmoid(go);
        float c_ = (s == 0) ? cA : cB;       // s compile-time (unrolled)
        c_ = f_ * c_ + i_ * g_;
        if (s == 0) cA = c_; else cB = c_;
        float hv = o_ * fast_tanh(c_);
        f16 hv16 = (f16)hv;
        llc_st16(h_all + ((size_t)t * B_ + sb16 + rl) * H_ + dd,
                 __builtin_bit_cast(unsigned short, hv16));
      }
      // store drains under the next phase's spin vmcnt(0); Hl double-buffer
      // makes a second barrier unnecessary (next staging hits the other buf).
    }
  }
}

// ---------------- logits: out[b][t][c] = relu(h[t+1]) . W_score[c] ----------------

__global__ __launch_bounds__(256) void k_logits(
    const f16* __restrict__ h_all, const float* __restrict__ wsc,
    float* __restrict__ out) {
  __shared__ float Ws[2048];
  unsigned tid = threadIdx.x;
  for (unsigned i = tid; i < 512; i += 256) ((float4*)Ws)[i] = ((const float4*)wsc)[i];
  __syncthreads();
  unsigned w = tid >> 6, lane = tid & 63;
  unsigned base = blockIdx.x * 64 + w * 16;
  for (unsigned i = 0; i < 16; ++i) {
    unsigned idx = base + i;                // 0..65535
    unsigned tt = idx >> 5, b = idx & 31;
    const f16* hp = h_all + ((size_t)(idx + 32)) * H_ + lane * 16;
    f16x8 ha = *(const f16x8*)hp;
    f16x8 hb = *(const f16x8*)(hp + 8);
    float s0 = 0.f, s1 = 0.f;
#pragma unroll
    for (int z = 0; z < 8; ++z) {
      float hv = fmaxf((float)ha[z], 0.f);
      s0 += hv * Ws[lane * 16 + z];
      s1 += hv * Ws[1024 + lane * 16 + z];
    }
#pragma unroll
    for (int z = 0; z < 8; ++z) {
      float hv = fmaxf((float)hb[z], 0.f);
      s0 += hv * Ws[lane * 16 + 8 + z];
      s1 += hv * Ws[1024 + lane * 16 + 8 + z];
    }
#pragma unroll
    for (int off = 32; off; off >>= 1) {
      s0 += __shfl_xor(s0, off, 64);
      s1 += __shfl_xor(s1, off, 64);
    }
    if (lane == 0) {
      out[((size_t)b * T_ + tt) * 2 + 0] = s0;
      out[((size_t)b * T_ + tt) * 2 + 1] = s1;
    }
  }
}

// ---------------- launch ----------------

extern "C" void kernel_launch(void* const* d_in, const int* in_sizes, int n_in,
                              void* d_out, int out_size, void* d_ws, size_t ws_size,
                              hipStream_t stream) {
  const int*   seq = (const int*)d_in[0];
  const float* emb = (const float*)d_in[1];
  const float* wih = (const float*)d_in[2];
  const float* whh = (const float*)d_in[3];
  const float* bih = (const float*)d_in[4];
  const float* bhh = (const float*)d_in[5];
  const float* wsc = (const float*)d_in[6];
  float* out = (float*)d_out;
  char* ws = (char*)d_ws;

  const size_t NEED = 790874112ull;
  if (ws_size < NEED) return;  // workspace too small: output stays zero (detectable)

  f16*   emb16 = (f16*)(ws);
  f16*   wih16 = (f16*)(ws + 102926336ull);
  f16*   wr16  = (f16*)(ws + 111314944ull);
  float* bias  = (float*)(ws + 119703552ull);
  f16*   xg    = (f16*)(ws + 119719936ull);
  f16*   h_all = (f16*)(ws + 656590848ull);

  hipMemsetAsync(h_all, 0, (size_t)B_ * H_ * 2, stream);                // h_0 = 0
  hipMemsetAsync((char*)h_all + (size_t)B_ * H_ * 2, 0xFF,
                 (size_t)T_ * B_ * H_ * 2, stream);                     // poison h_1..h_T

  k_cvt_f16<<<50257, 256, 0, stream>>>(emb, emb16, 12865792L);
  k_cvt_f16<<<4096, 256, 0, stream>>>(wih, wih16, 1048576L);
  k_whh_reorder<<<2048, 256, 0, stream>>>(whh, wr16);
  k_bias<<<16, 256, 0, stream>>>(bih, bhh, bias);

  k_gemm_xg<<<16384, 256, 0, stream>>>(seq, emb16, wih16, bias, xg);
  k_lstm<<<64, 256, 0, stream>>>(xg, wr16, h_all);
  k_logits<<<1024, 256, 0, stream>>>(h_all, wsc, out);
}